// Round 1
// 569.312 us; speedup vs baseline: 1.0357x; 1.0357x over previous
//
#include <hip/hip_runtime.h>
#include <hip/hip_bf16.h>
#include <math.h>

#define S_LEN  2048
#define DMODEL 2560
#define NHEADS 32
#define NKV    8
#define HD     128
#define QKDIM  (NHEADS * HD)   // 4096
#define KVDIM  (NKV * HD)      // 1024

typedef __bf16 bf16x8 __attribute__((ext_vector_type(8)));
typedef float  f32x4  __attribute__((ext_vector_type(4)));
typedef unsigned short u16;

#define AS1 __attribute__((address_space(1)))
#define AS3 __attribute__((address_space(3)))

__device__ __forceinline__ void load16_to_lds(const void* g, void* l) {
    __builtin_amdgcn_global_load_lds((const AS1 void*)g, (AS3 void*)l, 16, 0, 0);
}

__device__ __forceinline__ u16 f2bf(float f) {
    unsigned u = __builtin_bit_cast(unsigned, f);
    return (u16)((u + 0x7fff + ((u >> 16) & 1)) >> 16);   // RTNE
}

// ---------------------------------------------------------------------------
// Fused input convert: x | Wq | Wk | Wv -> bf16 in one launch.
// Weight outputs are contiguous (Wqb||Wkb||Wvb); x goes to its own dest.
// ---------------------------------------------------------------------------
#define N4_X   (S_LEN * DMODEL / 4)          // 1310720
#define N4_WQ  (QKDIM * DMODEL / 4)          // 2621440
#define N4_WK  (KVDIM * DMODEL / 4)          // 655360
#define N4_ALL (N4_X + N4_WQ + 2 * N4_WK)    // 5242880

__global__ __launch_bounds__(256) void convert_inputs(const float* __restrict__ x,
                                                      const float* __restrict__ wq,
                                                      const float* __restrict__ wk,
                                                      const float* __restrict__ wv,
                                                      u16* __restrict__ xb,
                                                      u16* __restrict__ wb) {
    const int stride = gridDim.x * 256;
    for (int i = blockIdx.x * 256 + threadIdx.x; i < N4_ALL; i += stride) {
        const float4* src;
        ushort4* dst;
        if (i < N4_X) {
            src = (const float4*)x + i;
            dst = (ushort4*)xb + i;
        } else {
            const int j = i - N4_X;
            dst = (ushort4*)wb + j;
            if (j < N4_WQ)                  src = (const float4*)wq + j;
            else if (j < N4_WQ + N4_WK)     src = (const float4*)wk + (j - N4_WQ);
            else                            src = (const float4*)wv + (j - N4_WQ - N4_WK);
        }
        float4 v = *src;
        ushort4 r;
        r.x = f2bf(v.x); r.y = f2bf(v.y); r.z = f2bf(v.z); r.w = f2bf(v.w);
        *dst = r;
    }
}

// ---------------------------------------------------------------------------
// fp32 -> bf16 convert, 4 elements/thread, grid-stride. n4 = n/4.
// ---------------------------------------------------------------------------
__global__ __launch_bounds__(256) void f32_to_bf16_k(const float* __restrict__ in,
                                                     u16* __restrict__ out, int n4) {
    int i = blockIdx.x * 256 + threadIdx.x;
    const int stride = gridDim.x * 256;
    for (; i < n4; i += stride) {
        float4 v = ((const float4*)in)[i];
        ushort4 r;
        r.x = f2bf(v.x); r.y = f2bf(v.y); r.z = f2bf(v.z); r.w = f2bf(v.w);
        ((ushort4*)out)[i] = r;
    }
}

// ---------------------------------------------------------------------------
// RoPE table: ct/st[s][i] fp32, computed in double (131K threads, trivial).
// ---------------------------------------------------------------------------
__global__ __launch_bounds__(64) void rope_table(float* __restrict__ ct,
                                                 float* __restrict__ st) {
    const int s = blockIdx.x;
    const int i = threadIdx.x;           // 0..63
    const double invf = pow(5.0e6, -(double)i / 64.0);
    const double ang  = (double)s * invf;
    ct[s * 64 + i] = (float)cos(ang);
    st[s * 64 + i] = (float)sin(ang);
}

// ---------------------------------------------------------------------------
// Output-projection GEMM, BK=64, double-buffered LDS (T3-min 2-phase:
// stage(t+1) issued BEFORE compute(t); ONE barrier per K-step so the
// vmcnt(0) drain at the barrier waits on loads that hid under the MFMAs).
// ---------------------------------------------------------------------------
__global__ __launch_bounds__(256) void gemm_bf16_nt(const __bf16* __restrict__ A,
                                                    const __bf16* __restrict__ B,
                                                    float* __restrict__ C,
                                                    int M, int N, int K) {
    __shared__ __align__(16) __bf16 Als[2][128 * 64];   // 32 KB
    __shared__ __align__(16) __bf16 Bls[2][128 * 64];   // 32 KB
    const int tid  = threadIdx.x;
    const int lane = tid & 63;
    const int wave = tid >> 6;
    const int wm   = wave >> 1, wn = wave & 1;
    const int m0   = blockIdx.y * 128;
    const int n0   = blockIdx.x * 128;
    const int frow = lane & 15;
    const int fkq  = lane >> 4;

    f32x4 acc[4][4];
#pragma unroll
    for (int t = 0; t < 4; ++t)
#pragma unroll
        for (int u = 0; u < 4; ++u)
            acc[t][u] = (f32x4){0.f, 0.f, 0.f, 0.f};

    // prologue: stage k0=0 into buffer 0
#pragma unroll
    for (int i = 0; i < 2; ++i) {
        const int mt  = i * 4 + wave;
        const int row = mt * 16 + frow;
#pragma unroll
        for (int kh = 0; kh < 2; ++kh) {
            const int col = kh * 32 + fkq * 8;
            load16_to_lds(A + (size_t)(m0 + row) * K + col,
                          &Als[0][(size_t)((mt * 2 + kh) * 64) * 8]);
            load16_to_lds(B + (size_t)(n0 + row) * K + col,
                          &Bls[0][(size_t)((mt * 2 + kh) * 64) * 8]);
        }
    }
    __syncthreads();   // drains vmcnt: buf0 staged

    int buf = 0;
    for (int k0 = 0; k0 < K; k0 += 64) {
        // issue next tile's loads into the other buffer (overlaps with MFMA)
        if (k0 + 64 < K) {
            const int nb = buf ^ 1;
            const int kn = k0 + 64;
#pragma unroll
            for (int i = 0; i < 2; ++i) {
                const int mt  = i * 4 + wave;
                const int row = mt * 16 + frow;
#pragma unroll
                for (int kh = 0; kh < 2; ++kh) {
                    const int col = kn + kh * 32 + fkq * 8;
                    load16_to_lds(A + (size_t)(m0 + row) * K + col,
                                  &Als[nb][(size_t)((mt * 2 + kh) * 64) * 8]);
                    load16_to_lds(B + (size_t)(n0 + row) * K + col,
                                  &Bls[nb][(size_t)((mt * 2 + kh) * 64) * 8]);
                }
            }
        }

        // compute current buffer
#pragma unroll
        for (int kh = 0; kh < 2; ++kh) {
            bf16x8 af[4], bfr[4];
#pragma unroll
            for (int t = 0; t < 4; ++t)
                af[t]  = *(const bf16x8*)&Als[buf][(((wm * 4 + t) * 2 + kh) * 64 + lane) * 8];
#pragma unroll
            for (int u = 0; u < 4; ++u)
                bfr[u] = *(const bf16x8*)&Bls[buf][(((wn * 4 + u) * 2 + kh) * 64 + lane) * 8];
#pragma unroll
            for (int t = 0; t < 4; ++t)
#pragma unroll
                for (int u = 0; u < 4; ++u)
                    acc[t][u] = __builtin_amdgcn_mfma_f32_16x16x32_bf16(
                                    af[t], bfr[u], acc[t][u], 0, 0, 0);
        }
        __syncthreads();   // one barrier/step: drains vmcnt (next buf staged)
                           // and lgkm (this buf's reads done)
        buf ^= 1;
    }

    const int crow = (lane >> 4) * 4;
    const int ccol = lane & 15;
#pragma unroll
    for (int t = 0; t < 4; ++t) {
        const int gr = m0 + (wm * 4 + t) * 16 + crow;
#pragma unroll
        for (int u = 0; u < 4; ++u) {
            const int gc = n0 + (wn * 4 + u) * 16 + ccol;
#pragma unroll
            for (int r = 0; r < 4; ++r)
                C[(size_t)(gr + r) * N + gc] = acc[t][u][r];
        }
    }
}

// ---------------------------------------------------------------------------
// Fused QKV GEMM + RMSNorm + RoPE + bf16 cast + V transpose, dbuf BK=64.
// grid (48,16). n-tile = exactly one head (BN == HD == 128), so the
// d=128 norm reduction is block-local. Waves own 32 rows x 128 cols
// (acc[2][8]) so the reduction is 8 in-register terms + 16-lane shuffle,
// and the RoPE partner d^64 is acc[t][u^4][r] in the SAME thread.
//   n-tile [0,32)  -> Q head h     : norm+rope, *0.12751743, -> qrb bf16
//   n-tile [32,40) -> K group g    : norm+rope -> cache_k fp32 + kcb bf16
//   n-tile [40,48) -> V group g    : raw -> cache_v fp32 + vtb bf16 [g][d][s]
// ---------------------------------------------------------------------------
__global__ __launch_bounds__(256) void gemm_qkv_fused(const __bf16* __restrict__ A,
                                                      const __bf16* __restrict__ Bq,
                                                      const __bf16* __restrict__ Bkv,
                                                      const float* __restrict__ ct,
                                                      const float* __restrict__ st,
                                                      const float* __restrict__ qw,
                                                      const float* __restrict__ kw,
                                                      u16*   __restrict__ qrb,
                                                      float* __restrict__ kc,
                                                      u16*   __restrict__ kcb,
                                                      float* __restrict__ vc,
                                                      u16*   __restrict__ vtb) {
    __shared__ __align__(16) __bf16 Als[2][128 * 64];
    __shared__ __align__(16) __bf16 Bls[2][128 * 64];
    const int K   = DMODEL;
    const int n0g = blockIdx.x * 128;
    const __bf16* B;
    int n0;
    if (n0g < QKDIM) { B = Bq;  n0 = n0g; }
    else             { B = Bkv; n0 = n0g - QKDIM; }   // rows of Wkb||Wvb

    const int tid  = threadIdx.x;
    const int lane = tid & 63;
    const int wave = tid >> 6;
    const int m0   = blockIdx.y * 128;
    const int frow = lane & 15;
    const int fkq  = lane >> 4;
    const int fr   = lane & 15;   // C/D col within 16x16
    const int fq   = lane >> 4;   // C/D row group

    f32x4 acc[2][8];
#pragma unroll
    for (int t = 0; t < 2; ++t)
#pragma unroll
        for (int u = 0; u < 8; ++u)
            acc[t][u] = (f32x4){0.f, 0.f, 0.f, 0.f};

    // prologue stage into buffer 0
#pragma unroll
    for (int i = 0; i < 2; ++i) {
        const int mt  = i * 4 + wave;
        const int row = mt * 16 + frow;
#pragma unroll
        for (int kh = 0; kh < 2; ++kh) {
            const int col = kh * 32 + fkq * 8;
            load16_to_lds(A + (size_t)(m0 + row) * K + col,
                          &Als[0][(size_t)((mt * 2 + kh) * 64) * 8]);
            load16_to_lds(B + (size_t)(n0 + row) * K + col,
                          &Bls[0][(size_t)((mt * 2 + kh) * 64) * 8]);
        }
    }
    __syncthreads();

    int buf = 0;
    for (int k0 = 0; k0 < K; k0 += 64) {
        if (k0 + 64 < K) {
            const int nb = buf ^ 1;
            const int kn = k0 + 64;
#pragma unroll
            for (int i = 0; i < 2; ++i) {
                const int mt  = i * 4 + wave;
                const int row = mt * 16 + frow;
#pragma unroll
                for (int kh = 0; kh < 2; ++kh) {
                    const int col = kn + kh * 32 + fkq * 8;
                    load16_to_lds(A + (size_t)(m0 + row) * K + col,
                                  &Als[nb][(size_t)((mt * 2 + kh) * 64) * 8]);
                    load16_to_lds(B + (size_t)(n0 + row) * K + col,
                                  &Bls[nb][(size_t)((mt * 2 + kh) * 64) * 8]);
                }
            }
        }

#pragma unroll
        for (int kh = 0; kh < 2; ++kh) {
            bf16x8 af[2], bfr[8];
#pragma unroll
            for (int t = 0; t < 2; ++t)
                af[t]  = *(const bf16x8*)&Als[buf][(((wave * 2 + t) * 2 + kh) * 64 + lane) * 8];
#pragma unroll
            for (int u = 0; u < 8; ++u)
                bfr[u] = *(const bf16x8*)&Bls[buf][((u * 2 + kh) * 64 + lane) * 8];
#pragma unroll
            for (int t = 0; t < 2; ++t)
#pragma unroll
                for (int u = 0; u < 8; ++u)
                    acc[t][u] = __builtin_amdgcn_mfma_f32_16x16x32_bf16(
                                    af[t], bfr[u], acc[t][u], 0, 0, 0);
        }
        __syncthreads();
        buf ^= 1;
    }

    // ------------------ fused epilogue ------------------
    // thread element (t,u,r): row s = m0 + wave*32 + t*16 + fq*4 + r,
    //                         col d = u*16 + fr   (d in [0,128) = head dim)
    if (n0g < QKDIM + KVDIM) {
        // Q or K: RMSNorm + RoPE
        const int isQ = (n0g < QKDIM) ? 1 : 0;
        const float* w = isQ ? qw : kw;
        float wv[8];
#pragma unroll
        for (int u = 0; u < 8; ++u) wv[u] = w[u * 16 + fr];

#pragma unroll
        for (int t = 0; t < 2; ++t) {
#pragma unroll
            for (int r = 0; r < 4; ++r) {
                float ss = 0.f;
#pragma unroll
                for (int u = 0; u < 8; ++u) ss += acc[t][u][r] * acc[t][u][r];
                ss += __shfl_xor(ss, 1);
                ss += __shfl_xor(ss, 2);
                ss += __shfl_xor(ss, 4);
                ss += __shfl_xor(ss, 8);
                const float rstd = rsqrtf(ss * (1.0f / 128.0f) + 1e-6f);
                const int s = m0 + wave * 32 + t * 16 + fq * 4 + r;
#pragma unroll
                for (int u = 0; u < 4; ++u) {
                    const float cs  = ct[s * 64 + u * 16 + fr];
                    const float sn  = st[s * 64 + u * 16 + fr];
                    const float ylo = acc[t][u][r]     * rstd * wv[u];
                    const float yhi = acc[t][u + 4][r] * rstd * wv[u + 4];
                    const float olo = ylo * cs - yhi * sn;
                    const float ohi = yhi * cs + ylo * sn;
                    if (isQ) {
                        const int h = n0g >> 7;
                        const size_t base = ((size_t)h * S_LEN + s) * HD;
                        qrb[base + u * 16 + fr]       = f2bf(olo * 0.12751743f);
                        qrb[base + (u + 4) * 16 + fr] = f2bf(ohi * 0.12751743f);
                    } else {
                        const int g = (n0g - QKDIM) >> 7;
                        const size_t base = ((size_t)g * S_LEN + s) * HD;
                        kc [base + u * 16 + fr]       = olo;
                        kc [base + (u + 4) * 16 + fr] = ohi;
                        kcb[base + u * 16 + fr]       = f2bf(olo);
                        kcb[base + (u + 4) * 16 + fr] = f2bf(ohi);
                    }
                }
            }
        }
    } else {
        // V: raw fp32 cache + transposed bf16 for attention
        const int g = (n0g - QKDIM - KVDIM) >> 7;
#pragma unroll
        for (int t = 0; t < 2; ++t) {
            const int sb = m0 + wave * 32 + t * 16 + fq * 4;   // 4 consecutive s
#pragma unroll
            for (int u = 0; u < 8; ++u) {
                const int d = u * 16 + fr;
                ushort4 o;
                o.x = f2bf(acc[t][u][0]); o.y = f2bf(acc[t][u][1]);
                o.z = f2bf(acc[t][u][2]); o.w = f2bf(acc[t][u][3]);
                *(ushort4*)&vtb[((size_t)g * HD + d) * S_LEN + sb] = o;
#pragma unroll
                for (int r = 0; r < 4; ++r)
                    vc[((size_t)g * S_LEN + sb + r) * HD + d] = acc[t][u][r];
            }
        }
    }
}

// ---------------------------------------------------------------------------
// MFMA flash attention (unchanged from verified round-4 version).
// ---------------------------------------------------------------------------
__global__ __launch_bounds__(256, 4) void attn_mfma(const __bf16* __restrict__ Qb,
                                                    const __bf16* __restrict__ Kb,
                                                    const __bf16* __restrict__ Vt,
                                                    u16* __restrict__ Ob) {
    __shared__ __align__(16) __bf16 Kls [4 * 4 * 64 * 8];  // 16KB
    __shared__ __align__(16) __bf16 QVls[8 * 2 * 64 * 8];  // 16KB (Q, then V)
    __shared__ __align__(16) __bf16 Pls [4 * 2 * 64 * 8];  // 8KB

    const int h    = blockIdx.x;
    const int g    = h >> 2;
    const int q0   = blockIdx.y * 64;
    const int tid  = threadIdx.x;
    const int lane = tid & 63;
    const int wave = tid >> 6;
    const int fr   = lane & 15;
    const int fq   = lane >> 4;

    {
        const __bf16* Qg = Qb + ((size_t)h * S_LEN + q0 + wave * 16 + fr) * HD;
#pragma unroll
        for (int ks = 0; ks < 4; ++ks)
            load16_to_lds(Qg + ks * 32 + fq * 8, &QVls[(size_t)((wave * 4 + ks) * 64) * 8]);
    }
    __syncthreads();
    bf16x8 aq[4];
#pragma unroll
    for (int ks = 0; ks < 4; ++ks)
        aq[ks] = *(const bf16x8*)&QVls[((wave * 4 + ks) * 64 + lane) * 8];

    float m_i[4], l_i[4];
    f32x4 o_acc[8];
#pragma unroll
    for (int r = 0; r < 4; ++r) { m_i[r] = -INFINITY; l_i[r] = 0.0f; }
#pragma unroll
    for (int dt = 0; dt < 8; ++dt) o_acc[dt] = (f32x4){0.f, 0.f, 0.f, 0.f};

    const int kt_max = blockIdx.y;
    for (int kt = 0; kt <= kt_max; ++kt) {
        __syncthreads();
        {
            const __bf16* Kg = Kb + ((size_t)g * S_LEN + kt * 64 + wave * 16 + fr) * HD;
#pragma unroll
            for (int ks = 0; ks < 4; ++ks)
                load16_to_lds(Kg + ks * 32 + fq * 8, &Kls[(size_t)((wave * 4 + ks) * 64) * 8]);
        }
#pragma unroll
        for (int i = 0; i < 2; ++i) {
            const int dt = wave * 2 + i;
            const __bf16* Vg = Vt + ((size_t)g * HD + dt * 16 + fr) * S_LEN + kt * 64;
#pragma unroll
            for (int ks = 0; ks < 2; ++ks)
                load16_to_lds(Vg + ks * 32 + fq * 8, &QVls[(size_t)((dt * 2 + ks) * 64) * 8]);
        }
        __syncthreads();

        f32x4 s_acc[4];
#pragma unroll
        for (int u = 0; u < 4; ++u) s_acc[u] = (f32x4){0.f, 0.f, 0.f, 0.f};
#pragma unroll
        for (int u = 0; u < 4; ++u)
#pragma unroll
            for (int ks = 0; ks < 4; ++ks)
                s_acc[u] = __builtin_amdgcn_mfma_f32_16x16x32_bf16(
                               aq[ks],
                               *(const bf16x8*)&Kls[((u * 4 + ks) * 64 + lane) * 8],
                               s_acc[u], 0, 0, 0);

        if (kt == kt_max) {
#pragma unroll
            for (int u = 0; u < 4; ++u)
#pragma unroll
                for (int r = 0; r < 4; ++r)
                    if (kt * 64 + u * 16 + fr > q0 + wave * 16 + fq * 4 + r)
                        s_acc[u][r] = -INFINITY;
        }

#pragma unroll
        for (int r = 0; r < 4; ++r) {
            float mx = fmaxf(fmaxf(s_acc[0][r], s_acc[1][r]),
                             fmaxf(s_acc[2][r], s_acc[3][r]));
#pragma unroll
            for (int off = 1; off < 16; off <<= 1)
                mx = fmaxf(mx, __shfl_xor(mx, off));
            const float m_new = fmaxf(m_i[r], mx);
            const float alpha = exp2f(m_i[r] - m_new);
            m_i[r] = m_new;

            float p[4], psum = 0.0f;
#pragma unroll
            for (int u = 0; u < 4; ++u) {
                p[u] = exp2f(s_acc[u][r] - m_new);
                psum += p[u];
            }
#pragma unroll
            for (int off = 1; off < 16; off <<= 1)
                psum += __shfl_xor(psum, off);
            l_i[r] = l_i[r] * alpha + psum;

#pragma unroll
            for (int dt = 0; dt < 8; ++dt) o_acc[dt][r] *= alpha;

#pragma unroll
            for (int u = 0; u < 4; ++u) {
                const int k = u * 16 + fr;
                const int m = fq * 4 + r;
                const int idx = ((wave * 2 + (k >> 5)) * 64 + ((k >> 3) & 3) * 16 + m) * 8
                                + (k & 7);
                ((u16*)Pls)[idx] = f2bf(p[u]);
            }
        }

        bf16x8 ap[2];
#pragma unroll
        for (int ks = 0; ks < 2; ++ks)
            ap[ks] = *(const bf16x8*)&Pls[((wave * 2 + ks) * 64 + lane) * 8];
#pragma unroll
        for (int dt = 0; dt < 8; ++dt)
#pragma unroll
            for (int ks = 0; ks < 2; ++ks)
                o_acc[dt] = __builtin_amdgcn_mfma_f32_16x16x32_bf16(
                                ap[ks],
                                *(const bf16x8*)&QVls[((dt * 2 + ks) * 64 + lane) * 8],
                                o_acc[dt], 0, 0, 0);
    }

#pragma unroll
    for (int r = 0; r < 4; ++r) {
        const float inv_l = 1.0f / l_i[r];
        const int s = q0 + wave * 16 + fq * 4 + r;
#pragma unroll
        for (int dt = 0; dt < 8; ++dt)
            Ob[(size_t)s * QKDIM + h * HD + dt * 16 + fr] = f2bf(o_acc[dt][r] * inv_l);
    }
}

// ---------------------------------------------------------------------------
extern "C" void kernel_launch(void* const* d_in, const int* in_sizes, int n_in,
                              void* d_out, int out_size, void* d_ws, size_t ws_size,
                              hipStream_t stream) {
    const float* x  = (const float*)d_in[0];
    const float* Wq = (const float*)d_in[1];
    const float* Wk = (const float*)d_in[2];
    const float* Wv = (const float*)d_in[3];
    const float* Wo = (const float*)d_in[4];
    const float* qw = (const float*)d_in[5];
    const float* kw = (const float*)d_in[6];

    float* out     = (float*)d_out;
    float* cache_k = out + (size_t)S_LEN * DMODEL;
    float* cache_v = cache_k + (size_t)NKV * S_LEN * HD;

    // ---- workspace layout (u16 units from base) ----
    // region A (live gemm_qkv..attn): qrb | kcb | vtb
    u16* wsu = (u16*)d_ws;
    u16* qrb = wsu;                                   // 32*2048*128 = 8,388,608
    u16* kcb = qrb + (size_t)NHEADS * S_LEN * HD;     // + 2,097,152
    u16* vtb = kcb + (size_t)NKV * S_LEN * HD;        // + 2,097,152
    // region B phase 1 (dead after gemm_qkv): bf16 weights, contiguous
    u16* Wqb = vtb + (size_t)NKV * S_LEN * HD;        // base 12,582,912
    u16* Wkb = Wqb + (size_t)QKDIM * DMODEL;
    // region B phase 2 overlay: attn out bf16 + Wo bf16
    u16* aob = Wqb;
    u16* Wob = aob + (size_t)S_LEN * QKDIM;
    // rope tables after overlay end (offset 31,457,280 u16 = 62.9 MB)
    float* ct = (float*)(Wqb + (size_t)S_LEN * QKDIM + (size_t)DMODEL * QKDIM);
    float* st = ct + S_LEN * 64;
    // x bf16 in d_out's out region (dead before final gemm writes out)
    u16* xb  = (u16*)out;

    // 1) input converts + rope tables (needed by fused gemm epilogue)
    convert_inputs<<<4096, 256, 0, stream>>>(x, Wq, Wk, Wv, xb, Wqb);
    rope_table<<<S_LEN, 64, 0, stream>>>(ct, st);

    // 2) fused QKV projection + RMSNorm + RoPE + casts + V transpose
    gemm_qkv_fused<<<dim3((QKDIM + 2 * KVDIM) / 128, S_LEN / 128), 256, 0, stream>>>(
        (const __bf16*)xb, (const __bf16*)Wqb, (const __bf16*)Wkb,
        ct, st, qw, kw, qrb, cache_k, kcb, cache_v, vtb);

    // 3) Wo convert (into region that overlays dead weights) + attention
    f32_to_bf16_k<<<1024, 256, 0, stream>>>(Wo, Wob, DMODEL * QKDIM / 4);
    attn_mfma<<<dim3(NHEADS, S_LEN / 64), 256, 0, stream>>>(
        (const __bf16*)qrb, (const __bf16*)kcb, (const __bf16*)vtb, aob);

    // 4) output projection (dbuf BK=64)
    gemm_bf16_nt<<<dim3(DMODEL / 128, S_LEN / 128), 256, 0, stream>>>(
        (const __bf16*)aob, (const __bf16*)Wob, out, S_LEN, DMODEL, QKDIM);
}

// Round 2
// 503.264 us; speedup vs baseline: 1.1717x; 1.1312x over previous
//
#include <hip/hip_runtime.h>
#include <hip/hip_bf16.h>
#include <math.h>

#define S_LEN  2048
#define DMODEL 2560
#define NHEADS 32
#define NKV    8
#define HD     128
#define QKDIM  (NHEADS * HD)   // 4096
#define KVDIM  (NKV * HD)      // 1024

typedef __bf16 bf16x8 __attribute__((ext_vector_type(8)));
typedef float  f32x4  __attribute__((ext_vector_type(4)));
typedef unsigned short u16;

#define AS1 __attribute__((address_space(1)))
#define AS3 __attribute__((address_space(3)))

__device__ __forceinline__ void load16_to_lds(const void* g, void* l) {
    __builtin_amdgcn_global_load_lds((const AS1 void*)g, (AS3 void*)l, 16, 0, 0);
}

__device__ __forceinline__ u16 f2bf(float f) {
    unsigned u = __builtin_bit_cast(unsigned, f);
    return (u16)((u + 0x7fff + ((u >> 16) & 1)) >> 16);   // RTNE
}

// phase-boundary helpers for the 8-phase schedule: raw s_barrier (NOT
// __syncthreads -- that drains vmcnt(0) and defeats counted prefetch),
// sched_barrier(0) pins plain-C++ ds_reads inside their phase (rule #18).
#define PHASE_BAR() do { __builtin_amdgcn_sched_barrier(0);            \
                         __builtin_amdgcn_s_barrier();                 \
                         __builtin_amdgcn_sched_barrier(0); } while (0)
#define WAIT_LGKM0() do { asm volatile("s_waitcnt lgkmcnt(0)" ::: "memory"); \
                          __builtin_amdgcn_sched_barrier(0); } while (0)

// st_16x32 swizzle (m201): byte ^= ((byte>>9)&1)<<5 within a half-tile
// [128 rows][64 cols] bf16 (row pitch 128B). Read side:
__device__ __forceinline__ const bf16x8* fragp(const __bf16* hbase, int row, int colb) {
    int b = (row << 7) | colb;
    b ^= ((b >> 9) & 1) << 5;
    return (const bf16x8*)((const char*)hbase + b);
}

// Staging: global_load_lds writes LINEARLY (wave-uniform base + lane*16);
// the swizzle is applied by pre-swizzling the per-lane GLOBAL source
// address (involution), so a swizzled read returns the right element.
// One call stages a 16KB half-tile: 8 waves x 2 instrs x 1KB.
__device__ __forceinline__ void stage_half(const __bf16* __restrict__ g0, int Kp,
                                           __bf16* l0, int wave, int lane) {
#pragma unroll
    for (int j = 0; j < 2; ++j) {
        const int p = ((wave * 2 + j) << 10) | (lane << 4);   // physical byte
        const int b = p ^ (((p >> 9) & 1) << 5);              // logical byte
        load16_to_lds((const char*)g0 + (size_t)(b >> 7) * (Kp * 2) + (b & 127),
                      (char*)l0 + ((wave * 2 + j) << 10));
    }
}

// ---------------------------------------------------------------------------
// Fused input convert: x | Wq | Wk | Wv -> bf16 in one launch.
// ---------------------------------------------------------------------------
#define N4_X   (S_LEN * DMODEL / 4)
#define N4_WQ  (QKDIM * DMODEL / 4)
#define N4_WK  (KVDIM * DMODEL / 4)
#define N4_ALL (N4_X + N4_WQ + 2 * N4_WK)

__global__ __launch_bounds__(256) void convert_inputs(const float* __restrict__ x,
                                                      const float* __restrict__ wq,
                                                      const float* __restrict__ wk,
                                                      const float* __restrict__ wv,
                                                      u16* __restrict__ xb,
                                                      u16* __restrict__ wb) {
    const int stride = gridDim.x * 256;
    for (int i = blockIdx.x * 256 + threadIdx.x; i < N4_ALL; i += stride) {
        const float4* src;
        ushort4* dst;
        if (i < N4_X) {
            src = (const float4*)x + i;
            dst = (ushort4*)xb + i;
        } else {
            const int j = i - N4_X;
            dst = (ushort4*)wb + j;
            if (j < N4_WQ)                  src = (const float4*)wq + j;
            else if (j < N4_WQ + N4_WK)     src = (const float4*)wk + (j - N4_WQ);
            else                            src = (const float4*)wv + (j - N4_WQ - N4_WK);
        }
        float4 v = *src;
        ushort4 r;
        r.x = f2bf(v.x); r.y = f2bf(v.y); r.z = f2bf(v.z); r.w = f2bf(v.w);
        *dst = r;
    }
}

__global__ __launch_bounds__(256) void f32_to_bf16_k(const float* __restrict__ in,
                                                     u16* __restrict__ out, int n4) {
    int i = blockIdx.x * 256 + threadIdx.x;
    const int stride = gridDim.x * 256;
    for (; i < n4; i += stride) {
        float4 v = ((const float4*)in)[i];
        ushort4 r;
        r.x = f2bf(v.x); r.y = f2bf(v.y); r.z = f2bf(v.z); r.w = f2bf(v.w);
        ((ushort4*)out)[i] = r;
    }
}

__global__ __launch_bounds__(64) void rope_table(float* __restrict__ ct,
                                                 float* __restrict__ st) {
    const int s = blockIdx.x;
    const int i = threadIdx.x;
    const double invf = pow(5.0e6, -(double)i / 64.0);
    const double ang  = (double)s * invf;
    ct[s * 64 + i] = (float)cos(ang);
    st[s * 64 + i] = (float)sin(ang);
}

// ---------------------------------------------------------------------------
// Output-projection GEMM: round-0 single-buffer structure (32KB LDS,
// 3 blocks/CU implicit overlap -- the proven-fast variant at this shape).
// ---------------------------------------------------------------------------
__global__ __launch_bounds__(256) void gemm_bf16_nt(const __bf16* __restrict__ A,
                                                    const __bf16* __restrict__ B,
                                                    float* __restrict__ C,
                                                    int M, int N, int K) {
    __shared__ __align__(16) __bf16 Als[128 * 64];
    __shared__ __align__(16) __bf16 Bls[128 * 64];
    const int tid  = threadIdx.x;
    const int lane = tid & 63;
    const int wave = tid >> 6;
    const int wm   = wave >> 1, wn = wave & 1;
    const int m0   = blockIdx.y * 128;
    const int n0   = blockIdx.x * 128;
    const int frow = lane & 15;
    const int fkq  = lane >> 4;

    f32x4 acc[4][4];
#pragma unroll
    for (int t = 0; t < 4; ++t)
#pragma unroll
        for (int u = 0; u < 4; ++u)
            acc[t][u] = (f32x4){0.f, 0.f, 0.f, 0.f};

    for (int k0 = 0; k0 < K; k0 += 64) {
        __syncthreads();
#pragma unroll
        for (int i = 0; i < 2; ++i) {
            const int mt  = i * 4 + wave;
            const int row = mt * 16 + frow;
#pragma unroll
            for (int kh = 0; kh < 2; ++kh) {
                const int col = k0 + kh * 32 + fkq * 8;
                load16_to_lds(A + (size_t)(m0 + row) * K + col,
                              &Als[(size_t)((mt * 2 + kh) * 64) * 8]);
                load16_to_lds(B + (size_t)(n0 + row) * K + col,
                              &Bls[(size_t)((mt * 2 + kh) * 64) * 8]);
            }
        }
        __syncthreads();

#pragma unroll
        for (int kh = 0; kh < 2; ++kh) {
            bf16x8 af[4], bfr[4];
#pragma unroll
            for (int t = 0; t < 4; ++t)
                af[t]  = *(const bf16x8*)&Als[(((wm * 4 + t) * 2 + kh) * 64 + lane) * 8];
#pragma unroll
            for (int u = 0; u < 4; ++u)
                bfr[u] = *(const bf16x8*)&Bls[(((wn * 4 + u) * 2 + kh) * 64 + lane) * 8];
#pragma unroll
            for (int t = 0; t < 4; ++t)
#pragma unroll
                for (int u = 0; u < 4; ++u)
                    acc[t][u] = __builtin_amdgcn_mfma_f32_16x16x32_bf16(
                                    af[t], bfr[u], acc[t][u], 0, 0, 0);
        }
    }

    const int crow = (lane >> 4) * 4;
    const int ccol = lane & 15;
#pragma unroll
    for (int t = 0; t < 4; ++t) {
        const int gr = m0 + (wm * 4 + t) * 16 + crow;
#pragma unroll
        for (int u = 0; u < 4; ++u) {
            const int gc = n0 + (wn * 4 + u) * 16 + ccol;
#pragma unroll
            for (int r = 0; r < 4; ++r)
                C[(size_t)(gr + r) * N + gc] = acc[t][u][r];
        }
    }
}

// ---------------------------------------------------------------------------
// 256x256 8-phase QKV GEMM (T2 st_16x32 swizzle + T3/T4 counted vmcnt +
// T5 setprio) with fused RMSNorm/RoPE/cast/V-transpose epilogue.
// 512 threads, 8 waves as 4M x 2N: each wave owns 64 rows x 128 cols =
// one full head-dim -> epilogue is entirely within-wave (round-1 verified).
// LDS 128KB: A/B x dbuf x 2 half-tiles of [128][64] bf16.
//
// Staging schedule (derived from read phases: A-halves last read ph2,
// B last read ph3 under quadrant order Q(m01,n03) Q(m23,n03) Q(m23,n47)
// Q(m01,n47)):  ph1: A1(kt+1) [other buf]   ph3: A0(kt+2) [same buf, safe]
//               ph4: B0,B1(kt+2)            vmcnt(6) once per K-tile.
// ---------------------------------------------------------------------------
__global__ __launch_bounds__(512, 2) void gemm_qkv_8ph(const __bf16* __restrict__ A,
                                                       const __bf16* __restrict__ Bq,
                                                       const __bf16* __restrict__ Bkv,
                                                       const float* __restrict__ ct,
                                                       const float* __restrict__ st,
                                                       const float* __restrict__ qw,
                                                       const float* __restrict__ kw,
                                                       u16*   __restrict__ qrb,
                                                       float* __restrict__ kc,
                                                       u16*   __restrict__ kcb,
                                                       float* __restrict__ vc,
                                                       u16*   __restrict__ vtb) {
    __shared__ __align__(16) __bf16 Als[4][128 * 64];   // [buf*2+half] 64KB
    __shared__ __align__(16) __bf16 Bls[4][128 * 64];   // 64KB

    const int K   = DMODEL;
    const int nkt = K / 64;                  // 40
    const int n0g = blockIdx.x * 256;
    const __bf16* B;
    int n0;
    if (n0g < QKDIM) { B = Bq;  n0 = n0g; }
    else             { B = Bkv; n0 = n0g - QKDIM; }
    const int m0 = blockIdx.y * 256;

    const int tid  = threadIdx.x;
    const int lane = tid & 63;
    const int wave = tid >> 6;
    const int wm   = wave >> 1;              // 0..3: 64-row band
    const int wn   = wave & 1;               // 0..1: 128-col half (one head)
    const int frow = lane & 15;
    const int fkq  = lane >> 4;
    const int ha   = wm >> 1;                // A half this wave reads
    const int ar0  = (wm & 1) * 64 + frow;   // base row within A half

    f32x4 acc[4][8];
#pragma unroll
    for (int t = 0; t < 4; ++t)
#pragma unroll
        for (int u = 0; u < 8; ++u)
            acc[t][u] = (f32x4){0.f, 0.f, 0.f, 0.f};

    // -------- prologue: kt0 (4 halves) + kt1 {A0,B0,B1}; vmcnt(6) => kt0 in
    stage_half(A + (size_t)m0 * K,               K, Als[0], wave, lane);
    stage_half(A + (size_t)(m0 + 128) * K,       K, Als[1], wave, lane);
    stage_half(B + (size_t)n0 * K,               K, Bls[0], wave, lane);
    stage_half(B + (size_t)(n0 + 128) * K,       K, Bls[1], wave, lane);
    stage_half(A + (size_t)m0 * K + 64,          K, Als[2], wave, lane);
    stage_half(B + (size_t)n0 * K + 64,          K, Bls[2], wave, lane);
    stage_half(B + (size_t)(n0 + 128) * K + 64,  K, Bls[3], wave, lane);
    asm volatile("s_waitcnt vmcnt(6)" ::: "memory");
    PHASE_BAR();

    for (int kt = 0; kt < nkt; ++kt) {
        const int bf = kt & 1;
        const __bf16* Ahb = Als[bf * 2 + ha];
        const __bf16* Bhb = Bls[bf * 2 + wn];

        // ================= phase 1: Q(m01, n0-3) =================
        bf16x8 a0[2][2], b0[4][2];
#pragma unroll
        for (int mt = 0; mt < 2; ++mt)
#pragma unroll
            for (int kh = 0; kh < 2; ++kh)
                a0[mt][kh] = *fragp(Ahb, ar0 + mt * 16, kh * 64 + fkq * 16);
#pragma unroll
        for (int nt = 0; nt < 4; ++nt)
#pragma unroll
            for (int kh = 0; kh < 2; ++kh)
                b0[nt][kh] = *fragp(Bhb, nt * 16 + frow, kh * 64 + fkq * 16);
        if (kt + 1 < nkt)
            stage_half(A + (size_t)(m0 + 128) * K + (kt + 1) * 64, K,
                       Als[(bf ^ 1) * 2 + 1], wave, lane);
        asm volatile("s_waitcnt lgkmcnt(8)" ::: "memory");
        PHASE_BAR();
        WAIT_LGKM0();
        __builtin_amdgcn_s_setprio(1);
#pragma unroll
        for (int mt = 0; mt < 2; ++mt)
#pragma unroll
            for (int nt = 0; nt < 4; ++nt)
#pragma unroll
                for (int kh = 0; kh < 2; ++kh)
                    acc[mt][nt] = __builtin_amdgcn_mfma_f32_16x16x32_bf16(
                                      a0[mt][kh], b0[nt][kh], acc[mt][nt], 0, 0, 0);
        __builtin_amdgcn_s_setprio(0);
        PHASE_BAR();

        // ================= phase 2: Q(m23, n0-3) =================
        bf16x8 a1[2][2];
#pragma unroll
        for (int mt = 0; mt < 2; ++mt)
#pragma unroll
            for (int kh = 0; kh < 2; ++kh)
                a1[mt][kh] = *fragp(Ahb, ar0 + 32 + mt * 16, kh * 64 + fkq * 16);
        PHASE_BAR();
        WAIT_LGKM0();
        __builtin_amdgcn_s_setprio(1);
#pragma unroll
        for (int mt = 0; mt < 2; ++mt)
#pragma unroll
            for (int nt = 0; nt < 4; ++nt)
#pragma unroll
                for (int kh = 0; kh < 2; ++kh)
                    acc[2 + mt][nt] = __builtin_amdgcn_mfma_f32_16x16x32_bf16(
                                          a1[mt][kh], b0[nt][kh], acc[2 + mt][nt], 0, 0, 0);
        __builtin_amdgcn_s_setprio(0);
        PHASE_BAR();

        // ================= phase 3: Q(m23, n4-7) =================
        bf16x8 b1[4][2];
#pragma unroll
        for (int nt = 0; nt < 4; ++nt)
#pragma unroll
            for (int kh = 0; kh < 2; ++kh)
                b1[nt][kh] = *fragp(Bhb, (4 + nt) * 16 + frow, kh * 64 + fkq * 16);
        if (kt + 2 < nkt)
            stage_half(A + (size_t)m0 * K + (kt + 2) * 64, K,
                       Als[bf * 2 + 0], wave, lane);
        PHASE_BAR();
        WAIT_LGKM0();
        __builtin_amdgcn_s_setprio(1);
#pragma unroll
        for (int mt = 0; mt < 2; ++mt)
#pragma unroll
            for (int nt = 0; nt < 4; ++nt)
#pragma unroll
                for (int kh = 0; kh < 2; ++kh)
                    acc[2 + mt][4 + nt] = __builtin_amdgcn_mfma_f32_16x16x32_bf16(
                                              a1[mt][kh], b1[nt][kh], acc[2 + mt][4 + nt], 0, 0, 0);
        __builtin_amdgcn_s_setprio(0);
        PHASE_BAR();

        // ================= phase 4: Q(m01, n4-7) =================
        if (kt + 2 < nkt) {
            stage_half(B + (size_t)n0 * K + (kt + 2) * 64,         K,
                       Bls[bf * 2 + 0], wave, lane);
            stage_half(B + (size_t)(n0 + 128) * K + (kt + 2) * 64, K,
                       Bls[bf * 2 + 1], wave, lane);
        }
        PHASE_BAR();
        WAIT_LGKM0();
        __builtin_amdgcn_s_setprio(1);
#pragma unroll
        for (int mt = 0; mt < 2; ++mt)
#pragma unroll
            for (int nt = 0; nt < 4; ++nt)
#pragma unroll
                for (int kh = 0; kh < 2; ++kh)
                    acc[mt][4 + nt] = __builtin_amdgcn_mfma_f32_16x16x32_bf16(
                                          a0[mt][kh], b1[nt][kh], acc[mt][4 + nt], 0, 0, 0);
        __builtin_amdgcn_s_setprio(0);
        if (kt < nkt - 2) asm volatile("s_waitcnt vmcnt(6)" ::: "memory");
        else              asm volatile("s_waitcnt vmcnt(0)" ::: "memory");
        PHASE_BAR();
    }

    // ------------------ fused epilogue (within-wave) ------------------
    // element (mt,u,r): row s = m0 + wm*64 + mt*16 + fq*4 + r,
    //                   col d = u*16 + fr  in head (n0g + wn*128)/128
    const int fr = frow;
    const int fq = fkq;
    const int nw = n0g + wn * 128;
    if (n0g < QKDIM + KVDIM) {
        const int isQ = (n0g < QKDIM) ? 1 : 0;
        const float* w = isQ ? qw : kw;
        float wv[8];
#pragma unroll
        for (int u = 0; u < 8; ++u) wv[u] = w[u * 16 + fr];

#pragma unroll
        for (int mt = 0; mt < 4; ++mt) {
#pragma unroll
            for (int r = 0; r < 4; ++r) {
                float ss = 0.f;
#pragma unroll
                for (int u = 0; u < 8; ++u) ss += acc[mt][u][r] * acc[mt][u][r];
                ss += __shfl_xor(ss, 1);
                ss += __shfl_xor(ss, 2);
                ss += __shfl_xor(ss, 4);
                ss += __shfl_xor(ss, 8);
                const float rstd = rsqrtf(ss * (1.0f / 128.0f) + 1e-6f);
                const int s = m0 + wm * 64 + mt * 16 + fq * 4 + r;
#pragma unroll
                for (int u = 0; u < 4; ++u) {
                    const float cs  = ct[s * 64 + u * 16 + fr];
                    const float sn  = st[s * 64 + u * 16 + fr];
                    const float ylo = acc[mt][u][r]     * rstd * wv[u];
                    const float yhi = acc[mt][u + 4][r] * rstd * wv[u + 4];
                    const float olo = ylo * cs - yhi * sn;
                    const float ohi = yhi * cs + ylo * sn;
                    if (isQ) {
                        const int h = nw >> 7;
                        const size_t base = ((size_t)h * S_LEN + s) * HD;
                        qrb[base + u * 16 + fr]       = f2bf(olo * 0.12751743f);
                        qrb[base + (u + 4) * 16 + fr] = f2bf(ohi * 0.12751743f);
                    } else {
                        const int g = (nw - QKDIM) >> 7;
                        const size_t base = ((size_t)g * S_LEN + s) * HD;
                        kc [base + u * 16 + fr]       = olo;
                        kc [base + (u + 4) * 16 + fr] = ohi;
                        kcb[base + u * 16 + fr]       = f2bf(olo);
                        kcb[base + (u + 4) * 16 + fr] = f2bf(ohi);
                    }
                }
            }
        }
    } else {
        const int g = (nw - QKDIM - KVDIM) >> 7;
#pragma unroll
        for (int mt = 0; mt < 4; ++mt) {
            const int sb = m0 + wm * 64 + mt * 16 + fq * 4;   // 4 consecutive s
#pragma unroll
            for (int u = 0; u < 8; ++u) {
                const int d = u * 16 + fr;
                ushort4 o;
                o.x = f2bf(acc[mt][u][0]); o.y = f2bf(acc[mt][u][1]);
                o.z = f2bf(acc[mt][u][2]); o.w = f2bf(acc[mt][u][3]);
                *(ushort4*)&vtb[((size_t)g * HD + d) * S_LEN + sb] = o;
#pragma unroll
                for (int r = 0; r < 4; ++r)
                    vc[((size_t)g * S_LEN + sb + r) * HD + d] = acc[mt][u][r];
            }
        }
    }
}

// ---------------------------------------------------------------------------
// MFMA flash attention (unchanged, verified).
// ---------------------------------------------------------------------------
__global__ __launch_bounds__(256, 4) void attn_mfma(const __bf16* __restrict__ Qb,
                                                    const __bf16* __restrict__ Kb,
                                                    const __bf16* __restrict__ Vt,
                                                    u16* __restrict__ Ob) {
    __shared__ __align__(16) __bf16 Kls [4 * 4 * 64 * 8];
    __shared__ __align__(16) __bf16 QVls[8 * 2 * 64 * 8];
    __shared__ __align__(16) __bf16 Pls [4 * 2 * 64 * 8];

    const int h    = blockIdx.x;
    const int g    = h >> 2;
    const int q0   = blockIdx.y * 64;
    const int tid  = threadIdx.x;
    const int lane = tid & 63;
    const int wave = tid >> 6;
    const int fr   = lane & 15;
    const int fq   = lane >> 4;

    {
        const __bf16* Qg = Qb + ((size_t)h * S_LEN + q0 + wave * 16 + fr) * HD;
#pragma unroll
        for (int ks = 0; ks < 4; ++ks)
            load16_to_lds(Qg + ks * 32 + fq * 8, &QVls[(size_t)((wave * 4 + ks) * 64) * 8]);
    }
    __syncthreads();
    bf16x8 aq[4];
#pragma unroll
    for (int ks = 0; ks < 4; ++ks)
        aq[ks] = *(const bf16x8*)&QVls[((wave * 4 + ks) * 64 + lane) * 8];

    float m_i[4], l_i[4];
    f32x4 o_acc[8];
#pragma unroll
    for (int r = 0; r < 4; ++r) { m_i[r] = -INFINITY; l_i[r] = 0.0f; }
#pragma unroll
    for (int dt = 0; dt < 8; ++dt) o_acc[dt] = (f32x4){0.f, 0.f, 0.f, 0.f};

    const int kt_max = blockIdx.y;
    for (int kt = 0; kt <= kt_max; ++kt) {
        __syncthreads();
        {
            const __bf16* Kg = Kb + ((size_t)g * S_LEN + kt * 64 + wave * 16 + fr) * HD;
#pragma unroll
            for (int ks = 0; ks < 4; ++ks)
                load16_to_lds(Kg + ks * 32 + fq * 8, &Kls[(size_t)((wave * 4 + ks) * 64) * 8]);
        }
#pragma unroll
        for (int i = 0; i < 2; ++i) {
            const int dt = wave * 2 + i;
            const __bf16* Vg = Vt + ((size_t)g * HD + dt * 16 + fr) * S_LEN + kt * 64;
#pragma unroll
            for (int ks = 0; ks < 2; ++ks)
                load16_to_lds(Vg + ks * 32 + fq * 8, &QVls[(size_t)((dt * 2 + ks) * 64) * 8]);
        }
        __syncthreads();

        f32x4 s_acc[4];
#pragma unroll
        for (int u = 0; u < 4; ++u) s_acc[u] = (f32x4){0.f, 0.f, 0.f, 0.f};
#pragma unroll
        for (int u = 0; u < 4; ++u)
#pragma unroll
            for (int ks = 0; ks < 4; ++ks)
                s_acc[u] = __builtin_amdgcn_mfma_f32_16x16x32_bf16(
                               aq[ks],
                               *(const bf16x8*)&Kls[((u * 4 + ks) * 64 + lane) * 8],
                               s_acc[u], 0, 0, 0);

        if (kt == kt_max) {
#pragma unroll
            for (int u = 0; u < 4; ++u)
#pragma unroll
                for (int r = 0; r < 4; ++r)
                    if (kt * 64 + u * 16 + fr > q0 + wave * 16 + fq * 4 + r)
                        s_acc[u][r] = -INFINITY;
        }

#pragma unroll
        for (int r = 0; r < 4; ++r) {
            float mx = fmaxf(fmaxf(s_acc[0][r], s_acc[1][r]),
                             fmaxf(s_acc[2][r], s_acc[3][r]));
#pragma unroll
            for (int off = 1; off < 16; off <<= 1)
                mx = fmaxf(mx, __shfl_xor(mx, off));
            const float m_new = fmaxf(m_i[r], mx);
            const float alpha = exp2f(m_i[r] - m_new);
            m_i[r] = m_new;

            float p[4], psum = 0.0f;
#pragma unroll
            for (int u = 0; u < 4; ++u) {
                p[u] = exp2f(s_acc[u][r] - m_new);
                psum += p[u];
            }
#pragma unroll
            for (int off = 1; off < 16; off <<= 1)
                psum += __shfl_xor(psum, off);
            l_i[r] = l_i[r] * alpha + psum;

#pragma unroll
            for (int dt = 0; dt < 8; ++dt) o_acc[dt][r] *= alpha;

#pragma unroll
            for (int u = 0; u < 4; ++u) {
                const int k = u * 16 + fr;
                const int m = fq * 4 + r;
                const int idx = ((wave * 2 + (k >> 5)) * 64 + ((k >> 3) & 3) * 16 + m) * 8
                                + (k & 7);
                ((u16*)Pls)[idx] = f2bf(p[u]);
            }
        }

        bf16x8 ap[2];
#pragma unroll
        for (int ks = 0; ks < 2; ++ks)
            ap[ks] = *(const bf16x8*)&Pls[((wave * 2 + ks) * 64 + lane) * 8];
#pragma unroll
        for (int dt = 0; dt < 8; ++dt)
#pragma unroll
            for (int ks = 0; ks < 2; ++ks)
                o_acc[dt] = __builtin_amdgcn_mfma_f32_16x16x32_bf16(
                                ap[ks],
                                *(const bf16x8*)&QVls[((dt * 2 + ks) * 64 + lane) * 8],
                                o_acc[dt], 0, 0, 0);
    }

#pragma unroll
    for (int r = 0; r < 4; ++r) {
        const float inv_l = 1.0f / l_i[r];
        const int s = q0 + wave * 16 + fq * 4 + r;
#pragma unroll
        for (int dt = 0; dt < 8; ++dt)
            Ob[(size_t)s * QKDIM + h * HD + dt * 16 + fr] = f2bf(o_acc[dt][r] * inv_l);
    }
}

// ---------------------------------------------------------------------------
extern "C" void kernel_launch(void* const* d_in, const int* in_sizes, int n_in,
                              void* d_out, int out_size, void* d_ws, size_t ws_size,
                              hipStream_t stream) {
    const float* x  = (const float*)d_in[0];
    const float* Wq = (const float*)d_in[1];
    const float* Wk = (const float*)d_in[2];
    const float* Wv = (const float*)d_in[3];
    const float* Wo = (const float*)d_in[4];
    const float* qw = (const float*)d_in[5];
    const float* kw = (const float*)d_in[6];

    float* out     = (float*)d_out;
    float* cache_k = out + (size_t)S_LEN * DMODEL;
    float* cache_v = cache_k + (size_t)NKV * S_LEN * HD;

    // ---- workspace layout (u16 units from base) ----
    u16* wsu = (u16*)d_ws;
    u16* qrb = wsu;
    u16* kcb = qrb + (size_t)NHEADS * S_LEN * HD;
    u16* vtb = kcb + (size_t)NKV * S_LEN * HD;
    u16* Wqb = vtb + (size_t)NKV * S_LEN * HD;
    u16* Wkb = Wqb + (size_t)QKDIM * DMODEL;
    u16* aob = Wqb;                               // overlay (weights dead)
    u16* Wob = aob + (size_t)S_LEN * QKDIM;
    float* ct = (float*)(Wqb + (size_t)S_LEN * QKDIM + (size_t)DMODEL * QKDIM);
    float* st = ct + S_LEN * 64;
    u16* xb  = (u16*)out;                         // x bf16 in out region

    // 1) input converts + rope tables
    convert_inputs<<<4096, 256, 0, stream>>>(x, Wq, Wk, Wv, xb, Wqb);
    rope_table<<<S_LEN, 64, 0, stream>>>(ct, st);

    // 2) 8-phase fused QKV projection + RMSNorm + RoPE + casts + V transpose
    gemm_qkv_8ph<<<dim3((QKDIM + 2 * KVDIM) / 256, S_LEN / 256), 512, 0, stream>>>(
        (const __bf16*)xb, (const __bf16*)Wqb, (const __bf16*)Wkb,
        ct, st, qw, kw, qrb, cache_k, kcb, cache_v, vtb);

    // 3) Wo convert + attention
    f32_to_bf16_k<<<1024, 256, 0, stream>>>(Wo, Wob, DMODEL * QKDIM / 4);
    attn_mfma<<<dim3(NHEADS, S_LEN / 64), 256, 0, stream>>>(
        (const __bf16*)qrb, (const __bf16*)kcb, (const __bf16*)vtb, aob);

    // 4) output projection (round-0 single-buffer structure)
    gemm_bf16_nt<<<dim3(DMODEL / 128, S_LEN / 128), 256, 0, stream>>>(
        (const __bf16*)aob, (const __bf16*)Wob, out, S_LEN, DMODEL, QKDIM);
}

// Round 3
// 484.863 us; speedup vs baseline: 1.2161x; 1.0380x over previous
//
#include <hip/hip_runtime.h>
#include <hip/hip_bf16.h>
#include <math.h>

#define S_LEN  2048
#define DMODEL 2560
#define NHEADS 32
#define NKV    8
#define HD     128
#define QKDIM  (NHEADS * HD)   // 4096
#define KVDIM  (NKV * HD)      // 1024

typedef __bf16 bf16x8 __attribute__((ext_vector_type(8)));
typedef float  f32x4  __attribute__((ext_vector_type(4)));
typedef unsigned short u16;

#define AS1 __attribute__((address_space(1)))
#define AS3 __attribute__((address_space(3)))

__device__ __forceinline__ void load16_to_lds(const void* g, void* l) {
    __builtin_amdgcn_global_load_lds((const AS1 void*)g, (AS3 void*)l, 16, 0, 0);
}

__device__ __forceinline__ u16 f2bf(float f) {
    unsigned u = __builtin_bit_cast(unsigned, f);
    return (u16)((u + 0x7fff + ((u >> 16) & 1)) >> 16);   // RTNE
}

// phase-boundary helpers for the 8-phase schedule: raw s_barrier (NOT
// __syncthreads -- that drains vmcnt(0) and defeats counted prefetch),
// sched_barrier(0) pins plain-C++ ds_reads inside their phase (rule #18).
#define PHASE_BAR() do { __builtin_amdgcn_sched_barrier(0);            \
                         __builtin_amdgcn_s_barrier();                 \
                         __builtin_amdgcn_sched_barrier(0); } while (0)
#define WAIT_LGKM0() do { asm volatile("s_waitcnt lgkmcnt(0)" ::: "memory"); \
                          __builtin_amdgcn_sched_barrier(0); } while (0)

// st_16x32 swizzle (m201): byte ^= ((byte>>9)&1)<<5 within a half-tile
// [128 rows][64 cols] bf16 (row pitch 128B). Read side:
__device__ __forceinline__ const bf16x8* fragp(const __bf16* hbase, int row, int colb) {
    int b = (row << 7) | colb;
    b ^= ((b >> 9) & 1) << 5;
    return (const bf16x8*)((const char*)hbase + b);
}

// Staging: global_load_lds writes LINEARLY (wave-uniform base + lane*16);
// the swizzle is applied by pre-swizzling the per-lane GLOBAL source
// address (involution), so a swizzled read returns the right element.
__device__ __forceinline__ void stage_half(const __bf16* __restrict__ g0, int Kp,
                                           __bf16* l0, int wave, int lane) {
#pragma unroll
    for (int j = 0; j < 2; ++j) {
        const int p = ((wave * 2 + j) << 10) | (lane << 4);   // physical byte
        const int b = p ^ (((p >> 9) & 1) << 5);              // logical byte
        load16_to_lds((const char*)g0 + (size_t)(b >> 7) * (Kp * 2) + (b & 127),
                      (char*)l0 + ((wave * 2 + j) << 10));
    }
}

// ---------------------------------------------------------------------------
// Fused input convert: x | Wq | Wk | Wv -> bf16 in one launch.
// ---------------------------------------------------------------------------
#define N4_X   (S_LEN * DMODEL / 4)
#define N4_WQ  (QKDIM * DMODEL / 4)
#define N4_WK  (KVDIM * DMODEL / 4)
#define N4_ALL (N4_X + N4_WQ + 2 * N4_WK)

__global__ __launch_bounds__(256) void convert_inputs(const float* __restrict__ x,
                                                      const float* __restrict__ wq,
                                                      const float* __restrict__ wk,
                                                      const float* __restrict__ wv,
                                                      u16* __restrict__ xb,
                                                      u16* __restrict__ wb) {
    const int stride = gridDim.x * 256;
    for (int i = blockIdx.x * 256 + threadIdx.x; i < N4_ALL; i += stride) {
        const float4* src;
        ushort4* dst;
        if (i < N4_X) {
            src = (const float4*)x + i;
            dst = (ushort4*)xb + i;
        } else {
            const int j = i - N4_X;
            dst = (ushort4*)wb + j;
            if (j < N4_WQ)                  src = (const float4*)wq + j;
            else if (j < N4_WQ + N4_WK)     src = (const float4*)wk + (j - N4_WQ);
            else                            src = (const float4*)wv + (j - N4_WQ - N4_WK);
        }
        float4 v = *src;
        ushort4 r;
        r.x = f2bf(v.x); r.y = f2bf(v.y); r.z = f2bf(v.z); r.w = f2bf(v.w);
        *dst = r;
    }
}

__global__ __launch_bounds__(256) void f32_to_bf16_k(const float* __restrict__ in,
                                                     u16* __restrict__ out, int n4) {
    int i = blockIdx.x * 256 + threadIdx.x;
    const int stride = gridDim.x * 256;
    for (; i < n4; i += stride) {
        float4 v = ((const float4*)in)[i];
        ushort4 r;
        r.x = f2bf(v.x); r.y = f2bf(v.y); r.z = f2bf(v.z); r.w = f2bf(v.w);
        ((ushort4*)out)[i] = r;
    }
}

__global__ __launch_bounds__(64) void rope_table(float* __restrict__ ct,
                                                 float* __restrict__ st) {
    const int s = blockIdx.x;
    const int i = threadIdx.x;
    const double invf = pow(5.0e6, -(double)i / 64.0);
    const double ang  = (double)s * invf;
    ct[s * 64 + i] = (float)cos(ang);
    st[s * 64 + i] = (float)sin(ang);
}

// ---------------------------------------------------------------------------
// Output-projection GEMM: round-0 single-buffer structure (32KB LDS,
// 3 blocks/CU implicit overlap -- the proven-fast variant at this shape).
// ---------------------------------------------------------------------------
__global__ __launch_bounds__(256) void gemm_bf16_nt(const __bf16* __restrict__ A,
                                                    const __bf16* __restrict__ B,
                                                    float* __restrict__ C,
                                                    int M, int N, int K) {
    __shared__ __align__(16) __bf16 Als[128 * 64];
    __shared__ __align__(16) __bf16 Bls[128 * 64];
    const int tid  = threadIdx.x;
    const int lane = tid & 63;
    const int wave = tid >> 6;
    const int wm   = wave >> 1, wn = wave & 1;
    const int m0   = blockIdx.y * 128;
    const int n0   = blockIdx.x * 128;
    const int frow = lane & 15;
    const int fkq  = lane >> 4;

    f32x4 acc[4][4];
#pragma unroll
    for (int t = 0; t < 4; ++t)
#pragma unroll
        for (int u = 0; u < 4; ++u)
            acc[t][u] = (f32x4){0.f, 0.f, 0.f, 0.f};

    for (int k0 = 0; k0 < K; k0 += 64) {
        __syncthreads();
#pragma unroll
        for (int i = 0; i < 2; ++i) {
            const int mt  = i * 4 + wave;
            const int row = mt * 16 + frow;
#pragma unroll
            for (int kh = 0; kh < 2; ++kh) {
                const int col = k0 + kh * 32 + fkq * 8;
                load16_to_lds(A + (size_t)(m0 + row) * K + col,
                              &Als[(size_t)((mt * 2 + kh) * 64) * 8]);
                load16_to_lds(B + (size_t)(n0 + row) * K + col,
                              &Bls[(size_t)((mt * 2 + kh) * 64) * 8]);
            }
        }
        __syncthreads();

#pragma unroll
        for (int kh = 0; kh < 2; ++kh) {
            bf16x8 af[4], bfr[4];
#pragma unroll
            for (int t = 0; t < 4; ++t)
                af[t]  = *(const bf16x8*)&Als[(((wm * 4 + t) * 2 + kh) * 64 + lane) * 8];
#pragma unroll
            for (int u = 0; u < 4; ++u)
                bfr[u] = *(const bf16x8*)&Bls[(((wn * 4 + u) * 2 + kh) * 64 + lane) * 8];
#pragma unroll
            for (int t = 0; t < 4; ++t)
#pragma unroll
                for (int u = 0; u < 4; ++u)
                    acc[t][u] = __builtin_amdgcn_mfma_f32_16x16x32_bf16(
                                    af[t], bfr[u], acc[t][u], 0, 0, 0);
        }
    }

    const int crow = (lane >> 4) * 4;
    const int ccol = lane & 15;
#pragma unroll
    for (int t = 0; t < 4; ++t) {
        const int gr = m0 + (wm * 4 + t) * 16 + crow;
#pragma unroll
        for (int u = 0; u < 4; ++u) {
            const int gc = n0 + (wn * 4 + u) * 16 + ccol;
#pragma unroll
            for (int r = 0; r < 4; ++r)
                C[(size_t)(gr + r) * N + gc] = acc[t][u][r];
        }
    }
}

// ---------------------------------------------------------------------------
// 256x256 8-phase QKV GEMM (T2 st_16x32 swizzle + T3/T4 counted vmcnt +
// T5 setprio) with fused RMSNorm/RoPE/cast/V-transpose epilogue.
// (verified round 2: gemm_qkv left the top-5)
// ---------------------------------------------------------------------------
__global__ __launch_bounds__(512, 2) void gemm_qkv_8ph(const __bf16* __restrict__ A,
                                                       const __bf16* __restrict__ Bq,
                                                       const __bf16* __restrict__ Bkv,
                                                       const float* __restrict__ ct,
                                                       const float* __restrict__ st,
                                                       const float* __restrict__ qw,
                                                       const float* __restrict__ kw,
                                                       u16*   __restrict__ qrb,
                                                       float* __restrict__ kc,
                                                       u16*   __restrict__ kcb,
                                                       float* __restrict__ vc,
                                                       u16*   __restrict__ vtb) {
    __shared__ __align__(16) __bf16 Als[4][128 * 64];   // [buf*2+half] 64KB
    __shared__ __align__(16) __bf16 Bls[4][128 * 64];   // 64KB

    const int K   = DMODEL;
    const int nkt = K / 64;                  // 40
    const int n0g = blockIdx.x * 256;
    const __bf16* B;
    int n0;
    if (n0g < QKDIM) { B = Bq;  n0 = n0g; }
    else             { B = Bkv; n0 = n0g - QKDIM; }
    const int m0 = blockIdx.y * 256;

    const int tid  = threadIdx.x;
    const int lane = tid & 63;
    const int wave = tid >> 6;
    const int wm   = wave >> 1;              // 0..3: 64-row band
    const int wn   = wave & 1;               // 0..1: 128-col half (one head)
    const int frow = lane & 15;
    const int fkq  = lane >> 4;
    const int ha   = wm >> 1;                // A half this wave reads
    const int ar0  = (wm & 1) * 64 + frow;   // base row within A half

    f32x4 acc[4][8];
#pragma unroll
    for (int t = 0; t < 4; ++t)
#pragma unroll
        for (int u = 0; u < 8; ++u)
            acc[t][u] = (f32x4){0.f, 0.f, 0.f, 0.f};

    // -------- prologue: kt0 (4 halves) + kt1 {A0,B0,B1}; vmcnt(6) => kt0 in
    stage_half(A + (size_t)m0 * K,               K, Als[0], wave, lane);
    stage_half(A + (size_t)(m0 + 128) * K,       K, Als[1], wave, lane);
    stage_half(B + (size_t)n0 * K,               K, Bls[0], wave, lane);
    stage_half(B + (size_t)(n0 + 128) * K,       K, Bls[1], wave, lane);
    stage_half(A + (size_t)m0 * K + 64,          K, Als[2], wave, lane);
    stage_half(B + (size_t)n0 * K + 64,          K, Bls[2], wave, lane);
    stage_half(B + (size_t)(n0 + 128) * K + 64,  K, Bls[3], wave, lane);
    asm volatile("s_waitcnt vmcnt(6)" ::: "memory");
    PHASE_BAR();

    for (int kt = 0; kt < nkt; ++kt) {
        const int bf = kt & 1;
        const __bf16* Ahb = Als[bf * 2 + ha];
        const __bf16* Bhb = Bls[bf * 2 + wn];

        // ================= phase 1: Q(m01, n0-3) =================
        bf16x8 a0[2][2], b0[4][2];
#pragma unroll
        for (int mt = 0; mt < 2; ++mt)
#pragma unroll
            for (int kh = 0; kh < 2; ++kh)
                a0[mt][kh] = *fragp(Ahb, ar0 + mt * 16, kh * 64 + fkq * 16);
#pragma unroll
        for (int nt = 0; nt < 4; ++nt)
#pragma unroll
            for (int kh = 0; kh < 2; ++kh)
                b0[nt][kh] = *fragp(Bhb, nt * 16 + frow, kh * 64 + fkq * 16);
        if (kt + 1 < nkt)
            stage_half(A + (size_t)(m0 + 128) * K + (kt + 1) * 64, K,
                       Als[(bf ^ 1) * 2 + 1], wave, lane);
        asm volatile("s_waitcnt lgkmcnt(8)" ::: "memory");
        PHASE_BAR();
        WAIT_LGKM0();
        __builtin_amdgcn_s_setprio(1);
#pragma unroll
        for (int mt = 0; mt < 2; ++mt)
#pragma unroll
            for (int nt = 0; nt < 4; ++nt)
#pragma unroll
                for (int kh = 0; kh < 2; ++kh)
                    acc[mt][nt] = __builtin_amdgcn_mfma_f32_16x16x32_bf16(
                                      a0[mt][kh], b0[nt][kh], acc[mt][nt], 0, 0, 0);
        __builtin_amdgcn_s_setprio(0);
        PHASE_BAR();

        // ================= phase 2: Q(m23, n0-3) =================
        bf16x8 a1[2][2];
#pragma unroll
        for (int mt = 0; mt < 2; ++mt)
#pragma unroll
            for (int kh = 0; kh < 2; ++kh)
                a1[mt][kh] = *fragp(Ahb, ar0 + 32 + mt * 16, kh * 64 + fkq * 16);
        PHASE_BAR();
        WAIT_LGKM0();
        __builtin_amdgcn_s_setprio(1);
#pragma unroll
        for (int mt = 0; mt < 2; ++mt)
#pragma unroll
            for (int nt = 0; nt < 4; ++nt)
#pragma unroll
                for (int kh = 0; kh < 2; ++kh)
                    acc[2 + mt][nt] = __builtin_amdgcn_mfma_f32_16x16x32_bf16(
                                          a1[mt][kh], b0[nt][kh], acc[2 + mt][nt], 0, 0, 0);
        __builtin_amdgcn_s_setprio(0);
        PHASE_BAR();

        // ================= phase 3: Q(m23, n4-7) =================
        bf16x8 b1[4][2];
#pragma unroll
        for (int nt = 0; nt < 4; ++nt)
#pragma unroll
            for (int kh = 0; kh < 2; ++kh)
                b1[nt][kh] = *fragp(Bhb, (4 + nt) * 16 + frow, kh * 64 + fkq * 16);
        if (kt + 2 < nkt)
            stage_half(A + (size_t)m0 * K + (kt + 2) * 64, K,
                       Als[bf * 2 + 0], wave, lane);
        PHASE_BAR();
        WAIT_LGKM0();
        __builtin_amdgcn_s_setprio(1);
#pragma unroll
        for (int mt = 0; mt < 2; ++mt)
#pragma unroll
            for (int nt = 0; nt < 4; ++nt)
#pragma unroll
                for (int kh = 0; kh < 2; ++kh)
                    acc[2 + mt][4 + nt] = __builtin_amdgcn_mfma_f32_16x16x32_bf16(
                                              a1[mt][kh], b1[nt][kh], acc[2 + mt][4 + nt], 0, 0, 0);
        __builtin_amdgcn_s_setprio(0);
        PHASE_BAR();

        // ================= phase 4: Q(m01, n4-7) =================
        if (kt + 2 < nkt) {
            stage_half(B + (size_t)n0 * K + (kt + 2) * 64,         K,
                       Bls[bf * 2 + 0], wave, lane);
            stage_half(B + (size_t)(n0 + 128) * K + (kt + 2) * 64, K,
                       Bls[bf * 2 + 1], wave, lane);
        }
        PHASE_BAR();
        WAIT_LGKM0();
        __builtin_amdgcn_s_setprio(1);
#pragma unroll
        for (int mt = 0; mt < 2; ++mt)
#pragma unroll
            for (int nt = 0; nt < 4; ++nt)
#pragma unroll
                for (int kh = 0; kh < 2; ++kh)
                    acc[mt][4 + nt] = __builtin_amdgcn_mfma_f32_16x16x32_bf16(
                                          a0[mt][kh], b1[nt][kh], acc[mt][4 + nt], 0, 0, 0);
        __builtin_amdgcn_s_setprio(0);
        if (kt < nkt - 2) asm volatile("s_waitcnt vmcnt(6)" ::: "memory");
        else              asm volatile("s_waitcnt vmcnt(0)" ::: "memory");
        PHASE_BAR();
    }

    // ------------------ fused epilogue (within-wave) ------------------
    const int fr = frow;
    const int fq = fkq;
    const int nw = n0g + wn * 128;
    if (n0g < QKDIM + KVDIM) {
        const int isQ = (n0g < QKDIM) ? 1 : 0;
        const float* w = isQ ? qw : kw;
        float wv[8];
#pragma unroll
        for (int u = 0; u < 8; ++u) wv[u] = w[u * 16 + fr];

#pragma unroll
        for (int mt = 0; mt < 4; ++mt) {
#pragma unroll
            for (int r = 0; r < 4; ++r) {
                float ss = 0.f;
#pragma unroll
                for (int u = 0; u < 8; ++u) ss += acc[mt][u][r] * acc[mt][u][r];
                ss += __shfl_xor(ss, 1);
                ss += __shfl_xor(ss, 2);
                ss += __shfl_xor(ss, 4);
                ss += __shfl_xor(ss, 8);
                const float rstd = rsqrtf(ss * (1.0f / 128.0f) + 1e-6f);
                const int s = m0 + wm * 64 + mt * 16 + fq * 4 + r;
#pragma unroll
                for (int u = 0; u < 4; ++u) {
                    const float cs  = ct[s * 64 + u * 16 + fr];
                    const float sn  = st[s * 64 + u * 16 + fr];
                    const float ylo = acc[mt][u][r]     * rstd * wv[u];
                    const float yhi = acc[mt][u + 4][r] * rstd * wv[u + 4];
                    const float olo = ylo * cs - yhi * sn;
                    const float ohi = yhi * cs + ylo * sn;
                    if (isQ) {
                        const int h = nw >> 7;
                        const size_t base = ((size_t)h * S_LEN + s) * HD;
                        qrb[base + u * 16 + fr]       = f2bf(olo * 0.12751743f);
                        qrb[base + (u + 4) * 16 + fr] = f2bf(ohi * 0.12751743f);
                    } else {
                        const int g = (nw - QKDIM) >> 7;
                        const size_t base = ((size_t)g * S_LEN + s) * HD;
                        kc [base + u * 16 + fr]       = olo;
                        kc [base + (u + 4) * 16 + fr] = ohi;
                        kcb[base + u * 16 + fr]       = f2bf(olo);
                        kcb[base + (u + 4) * 16 + fr] = f2bf(ohi);
                    }
                }
            }
        }
    } else {
        const int g = (nw - QKDIM - KVDIM) >> 7;
#pragma unroll
        for (int mt = 0; mt < 4; ++mt) {
            const int sb = m0 + wm * 64 + mt * 16 + fq * 4;   // 4 consecutive s
#pragma unroll
            for (int u = 0; u < 8; ++u) {
                const int d = u * 16 + fr;
                ushort4 o;
                o.x = f2bf(acc[mt][u][0]); o.y = f2bf(acc[mt][u][1]);
                o.z = f2bf(acc[mt][u][2]); o.w = f2bf(acc[mt][u][3]);
                *(ushort4*)&vtb[((size_t)g * HD + d) * S_LEN + sb] = o;
#pragma unroll
                for (int r = 0; r < 4; ++r)
                    vc[((size_t)g * S_LEN + sb + r) * HD + d] = acc[mt][u][r];
            }
        }
    }
}

// ---------------------------------------------------------------------------
// Flash attention, round 3: causal-PAIRED q-tiles + async dbuf K/V staging.
// Block (h, y) handles q-tiles {y, 31-y} of head h: every block does exactly
// 33 tile-computes over 32 staged k-tiles (uniform work, K/V staging traffic
// halved, 2x MFMA per staged tile while both tiles active).
// Stage(kt+1) is issued at the TOP of iteration kt; the single end-of-iter
// __syncthreads' vmcnt(0) drain waits on loads that had the whole
// QK^T+softmax+PV phase to land (T3-minimum / T14 async-stage).
// LDS: K dbuf 32KB + V dbuf 32KB + P 8KB = 72KB -> 2 blocks/CU; grid 512.
// ---------------------------------------------------------------------------
__device__ __forceinline__ void attn_tile_compute(
        const bf16x8 aq[4], f32x4 o_acc[8], float m_i[4], float l_i[4],
        const __bf16* __restrict__ Kl, const __bf16* __restrict__ Vl,
        __bf16* __restrict__ Pls, int lane, int wave, int fr, int fq,
        int qrow0, int kbase, bool diag) {
    f32x4 s_acc[4];
#pragma unroll
    for (int u = 0; u < 4; ++u) s_acc[u] = (f32x4){0.f, 0.f, 0.f, 0.f};
    __builtin_amdgcn_s_setprio(1);
#pragma unroll
    for (int u = 0; u < 4; ++u)
#pragma unroll
        for (int ks = 0; ks < 4; ++ks)
            s_acc[u] = __builtin_amdgcn_mfma_f32_16x16x32_bf16(
                           aq[ks],
                           *(const bf16x8*)&Kl[((u * 4 + ks) * 64 + lane) * 8],
                           s_acc[u], 0, 0, 0);
    __builtin_amdgcn_s_setprio(0);

    if (diag) {
#pragma unroll
        for (int u = 0; u < 4; ++u)
#pragma unroll
            for (int r = 0; r < 4; ++r)
                if (kbase + u * 16 + fr > qrow0 + fq * 4 + r)
                    s_acc[u][r] = -INFINITY;
    }

#pragma unroll
    for (int r = 0; r < 4; ++r) {
        float mx = fmaxf(fmaxf(s_acc[0][r], s_acc[1][r]),
                         fmaxf(s_acc[2][r], s_acc[3][r]));
#pragma unroll
        for (int off = 1; off < 16; off <<= 1)
            mx = fmaxf(mx, __shfl_xor(mx, off));
        const float m_new = fmaxf(m_i[r], mx);
        const float alpha = exp2f(m_i[r] - m_new);
        m_i[r] = m_new;

        float p[4], psum = 0.0f;
#pragma unroll
        for (int u = 0; u < 4; ++u) {
            p[u] = exp2f(s_acc[u][r] - m_new);
            psum += p[u];
        }
#pragma unroll
        for (int off = 1; off < 16; off <<= 1)
            psum += __shfl_xor(psum, off);
        l_i[r] = l_i[r] * alpha + psum;

#pragma unroll
        for (int dt = 0; dt < 8; ++dt) o_acc[dt][r] *= alpha;

#pragma unroll
        for (int u = 0; u < 4; ++u) {
            const int k = u * 16 + fr;
            const int m = fq * 4 + r;
            const int idx = ((wave * 2 + (k >> 5)) * 64 + ((k >> 3) & 3) * 16 + m) * 8
                            + (k & 7);
            ((u16*)Pls)[idx] = f2bf(p[u]);
        }
    }

    bf16x8 ap[2];
#pragma unroll
    for (int ks = 0; ks < 2; ++ks)
        ap[ks] = *(const bf16x8*)&Pls[((wave * 2 + ks) * 64 + lane) * 8];
    __builtin_amdgcn_s_setprio(1);
#pragma unroll
    for (int dt = 0; dt < 8; ++dt)
#pragma unroll
        for (int ks = 0; ks < 2; ++ks)
            o_acc[dt] = __builtin_amdgcn_mfma_f32_16x16x32_bf16(
                            ap[ks],
                            *(const bf16x8*)&Vl[((dt * 2 + ks) * 64 + lane) * 8],
                            o_acc[dt], 0, 0, 0);
    __builtin_amdgcn_s_setprio(0);
}

__global__ __launch_bounds__(256) void attn_mfma(const __bf16* __restrict__ Qb,
                                                 const __bf16* __restrict__ Kb,
                                                 const __bf16* __restrict__ Vt,
                                                 u16* __restrict__ Ob) {
    __shared__ __align__(16) __bf16 Kls[2][16 * 64 * 8];  // 2 x 16KB
    __shared__ __align__(16) __bf16 Vls[2][16 * 64 * 8];  // 2 x 16KB
    __shared__ __align__(16) __bf16 Pls[8 * 64 * 8];      // 8KB

    const int h    = blockIdx.x;
    const int g    = h >> 2;
    const int pair = blockIdx.y;                 // 0..15
    const int ytl  = pair;                       // low q-tile
    const int yth  = (S_LEN / 64 - 1) - pair;    // high q-tile
    const int q0l  = ytl * 64;
    const int q0h  = yth * 64;
    const int tid  = threadIdx.x;
    const int lane = tid & 63;
    const int wave = tid >> 6;
    const int fr   = lane & 15;
    const int fq   = lane >> 4;

    // stage both Q tiles (hi -> Kls[0], lo -> Kls[1]), hoist to regs
    {
        const __bf16* Qh = Qb + ((size_t)h * S_LEN + q0h + wave * 16 + fr) * HD;
        const __bf16* Ql = Qb + ((size_t)h * S_LEN + q0l + wave * 16 + fr) * HD;
#pragma unroll
        for (int ks = 0; ks < 4; ++ks) {
            load16_to_lds(Qh + ks * 32 + fq * 8, &Kls[0][(size_t)((wave * 4 + ks) * 64) * 8]);
            load16_to_lds(Ql + ks * 32 + fq * 8, &Kls[1][(size_t)((wave * 4 + ks) * 64) * 8]);
        }
    }
    __syncthreads();
    bf16x8 aqh[4], aql[4];
#pragma unroll
    for (int ks = 0; ks < 4; ++ks) {
        aqh[ks] = *(const bf16x8*)&Kls[0][((wave * 4 + ks) * 64 + lane) * 8];
        aql[ks] = *(const bf16x8*)&Kls[1][((wave * 4 + ks) * 64 + lane) * 8];
    }
    __syncthreads();   // reg hoist complete before Kls reused for K

    float m_h[4], l_h[4], m_l[4], l_l[4];
    f32x4 o_h[8], o_l[8];
#pragma unroll
    for (int r = 0; r < 4; ++r) {
        m_h[r] = -INFINITY; l_h[r] = 0.0f;
        m_l[r] = -INFINITY; l_l[r] = 0.0f;
    }
#pragma unroll
    for (int dt = 0; dt < 8; ++dt) {
        o_h[dt] = (f32x4){0.f, 0.f, 0.f, 0.f};
        o_l[dt] = (f32x4){0.f, 0.f, 0.f, 0.f};
    }

    // stage kt=0
    {
        const __bf16* Kg = Kb + ((size_t)g * S_LEN + wave * 16 + fr) * HD;
#pragma unroll
        for (int ks = 0; ks < 4; ++ks)
            load16_to_lds(Kg + ks * 32 + fq * 8, &Kls[0][(size_t)((wave * 4 + ks) * 64) * 8]);
#pragma unroll
        for (int i = 0; i < 2; ++i) {
            const int dt = wave * 2 + i;
            const __bf16* Vg = Vt + ((size_t)g * HD + dt * 16 + fr) * S_LEN;
#pragma unroll
            for (int ks = 0; ks < 2; ++ks)
                load16_to_lds(Vg + ks * 32 + fq * 8, &Vls[0][(size_t)((dt * 2 + ks) * 64) * 8]);
        }
    }
    __syncthreads();   // kt=0 staged

    for (int kt = 0; kt <= yth; ++kt) {
        const int buf = kt & 1;
        // issue next tile's stage into the other buffer (hidden under compute)
        if (kt < yth) {
            const int nb = buf ^ 1;
            const __bf16* Kg = Kb + ((size_t)g * S_LEN + (kt + 1) * 64 + wave * 16 + fr) * HD;
#pragma unroll
            for (int ks = 0; ks < 4; ++ks)
                load16_to_lds(Kg + ks * 32 + fq * 8, &Kls[nb][(size_t)((wave * 4 + ks) * 64) * 8]);
#pragma unroll
            for (int i = 0; i < 2; ++i) {
                const int dt = wave * 2 + i;
                const __bf16* Vg = Vt + ((size_t)g * HD + dt * 16 + fr) * S_LEN + (kt + 1) * 64;
#pragma unroll
                for (int ks = 0; ks < 2; ++ks)
                    load16_to_lds(Vg + ks * 32 + fq * 8, &Vls[nb][(size_t)((dt * 2 + ks) * 64) * 8]);
            }
        }

        // high q-tile: always active
        attn_tile_compute(aqh, o_h, m_h, l_h, Kls[buf], Vls[buf], Pls,
                          lane, wave, fr, fq, q0h + wave * 16, kt * 64, kt == yth);
        // low q-tile: active while kt <= ytl
        if (kt <= ytl)
            attn_tile_compute(aql, o_l, m_l, l_l, Kls[buf], Vls[buf], Pls,
                              lane, wave, fr, fq, q0l + wave * 16, kt * 64, kt == ytl);

        __syncthreads();   // drains vmcnt (next buf staged) + LDS reuse safe
    }

    // ---- epilogue: both tiles ----
#pragma unroll
    for (int r = 0; r < 4; ++r) {
        const float ih = 1.0f / l_h[r];
        const float il = 1.0f / l_l[r];
        const int sh = q0h + wave * 16 + fq * 4 + r;
        const int sl = q0l + wave * 16 + fq * 4 + r;
#pragma unroll
        for (int dt = 0; dt < 8; ++dt) {
            Ob[(size_t)sh * QKDIM + h * HD + dt * 16 + fr] = f2bf(o_h[dt][r] * ih);
            Ob[(size_t)sl * QKDIM + h * HD + dt * 16 + fr] = f2bf(o_l[dt][r] * il);
        }
    }
}

// ---------------------------------------------------------------------------
extern "C" void kernel_launch(void* const* d_in, const int* in_sizes, int n_in,
                              void* d_out, int out_size, void* d_ws, size_t ws_size,
                              hipStream_t stream) {
    const float* x  = (const float*)d_in[0];
    const float* Wq = (const float*)d_in[1];
    const float* Wk = (const float*)d_in[2];
    const float* Wv = (const float*)d_in[3];
    const float* Wo = (const float*)d_in[4];
    const float* qw = (const float*)d_in[5];
    const float* kw = (const float*)d_in[6];

    float* out     = (float*)d_out;
    float* cache_k = out + (size_t)S_LEN * DMODEL;
    float* cache_v = cache_k + (size_t)NKV * S_LEN * HD;

    // ---- workspace layout (u16 units from base) ----
    u16* wsu = (u16*)d_ws;
    u16* qrb = wsu;
    u16* kcb = qrb + (size_t)NHEADS * S_LEN * HD;
    u16* vtb = kcb + (size_t)NKV * S_LEN * HD;
    u16* Wqb = vtb + (size_t)NKV * S_LEN * HD;
    u16* Wkb = Wqb + (size_t)QKDIM * DMODEL;
    u16* aob = Wqb;                               // overlay (weights dead)
    u16* Wob = aob + (size_t)S_LEN * QKDIM;
    float* ct = (float*)(Wqb + (size_t)S_LEN * QKDIM + (size_t)DMODEL * QKDIM);
    float* st = ct + S_LEN * 64;
    u16* xb  = (u16*)out;                         // x bf16 in out region

    // 1) input converts + rope tables
    convert_inputs<<<4096, 256, 0, stream>>>(x, Wq, Wk, Wv, xb, Wqb);
    rope_table<<<S_LEN, 64, 0, stream>>>(ct, st);

    // 2) 8-phase fused QKV projection + RMSNorm + RoPE + casts + V transpose
    gemm_qkv_8ph<<<dim3((QKDIM + 2 * KVDIM) / 256, S_LEN / 256), 512, 0, stream>>>(
        (const __bf16*)xb, (const __bf16*)Wqb, (const __bf16*)Wkb,
        ct, st, qw, kw, qrb, cache_k, kcb, cache_v, vtb);

    // 3) Wo convert + attention (paired causal tiles, async dbuf staging)
    f32_to_bf16_k<<<1024, 256, 0, stream>>>(Wo, Wob, DMODEL * QKDIM / 4);
    attn_mfma<<<dim3(NHEADS, S_LEN / 128), 256, 0, stream>>>(
        (const __bf16*)qrb, (const __bf16*)kcb, (const __bf16*)vtb, aob);

    // 4) output projection (round-0 single-buffer structure)
    gemm_bf16_nt<<<dim3(DMODEL / 128, S_LEN / 128), 256, 0, stream>>>(
        (const __bf16*)aob, (const __bf16*)Wob, out, S_LEN, DMODEL, QKDIM);
}

// Round 4
// 454.980 us; speedup vs baseline: 1.2960x; 1.0657x over previous
//
#include <hip/hip_runtime.h>
#include <hip/hip_bf16.h>
#include <math.h>

#define S_LEN  2048
#define DMODEL 2560
#define NHEADS 32
#define NKV    8
#define HD     128
#define QKDIM  (NHEADS * HD)   // 4096
#define KVDIM  (NKV * HD)      // 1024

typedef __bf16 bf16x8 __attribute__((ext_vector_type(8)));
typedef float  f32x4  __attribute__((ext_vector_type(4)));
typedef unsigned short u16;

#define AS1 __attribute__((address_space(1)))
#define AS3 __attribute__((address_space(3)))

__device__ __forceinline__ void load16_to_lds(const void* g, void* l) {
    __builtin_amdgcn_global_load_lds((const AS1 void*)g, (AS3 void*)l, 16, 0, 0);
}

__device__ __forceinline__ u16 f2bf(float f) {
    unsigned u = __builtin_bit_cast(unsigned, f);
    return (u16)((u + 0x7fff + ((u >> 16) & 1)) >> 16);   // RTNE
}

// phase-boundary helpers (raw s_barrier; sched_barrier pins ds_reads, rule #18)
#define PHASE_BAR() do { __builtin_amdgcn_sched_barrier(0);            \
                         __builtin_amdgcn_s_barrier();                 \
                         __builtin_amdgcn_sched_barrier(0); } while (0)
#define WAIT_LGKM0() do { asm volatile("s_waitcnt lgkmcnt(0)" ::: "memory"); \
                          __builtin_amdgcn_sched_barrier(0); } while (0)

// LDS XOR-swizzle, 3-bit (G4-verified form): byte ^= ((row&7)<<4) for a
// [128 rows][64 cols] bf16 half-tile (row pitch 128B). 16 same-column lanes
// spread across all 8 16B slots (2-way residual = free). Involution on
// bits 4-6 keyed by row bits (7-9) -> stage/read pair stays consistent.
__device__ __forceinline__ const bf16x8* fragp(const __bf16* hbase, int row, int colb) {
    int b = (row << 7) | colb;
    b ^= ((b >> 7) & 7) << 4;
    return (const bf16x8*)((const char*)hbase + b);
}

// Staging: global_load_lds writes LINEARLY; swizzle applied by pre-swizzling
// the per-lane GLOBAL source address (same involution).
__device__ __forceinline__ void stage_half(const __bf16* __restrict__ g0, int Kp,
                                           __bf16* l0, int wave, int lane) {
#pragma unroll
    for (int j = 0; j < 2; ++j) {
        const int p = ((wave * 2 + j) << 10) | (lane << 4);   // physical byte
        const int b = p ^ (((p >> 7) & 7) << 4);              // logical byte
        load16_to_lds((const char*)g0 + (size_t)(b >> 7) * (Kp * 2) + (b & 127),
                      (char*)l0 + ((wave * 2 + j) << 10));
    }
}

// ---------------------------------------------------------------------------
// Fused input convert: x | Wq | Wk | Wv -> bf16 in one launch.
// ---------------------------------------------------------------------------
#define N4_X   (S_LEN * DMODEL / 4)
#define N4_WQ  (QKDIM * DMODEL / 4)
#define N4_WK  (KVDIM * DMODEL / 4)
#define N4_ALL (N4_X + N4_WQ + 2 * N4_WK)

__global__ __launch_bounds__(256) void convert_inputs(const float* __restrict__ x,
                                                      const float* __restrict__ wq,
                                                      const float* __restrict__ wk,
                                                      const float* __restrict__ wv,
                                                      u16* __restrict__ xb,
                                                      u16* __restrict__ wb) {
    const int stride = gridDim.x * 256;
    for (int i = blockIdx.x * 256 + threadIdx.x; i < N4_ALL; i += stride) {
        const float4* src;
        ushort4* dst;
        if (i < N4_X) {
            src = (const float4*)x + i;
            dst = (ushort4*)xb + i;
        } else {
            const int j = i - N4_X;
            dst = (ushort4*)wb + j;
            if (j < N4_WQ)                  src = (const float4*)wq + j;
            else if (j < N4_WQ + N4_WK)     src = (const float4*)wk + (j - N4_WQ);
            else                            src = (const float4*)wv + (j - N4_WQ - N4_WK);
        }
        float4 v = *src;
        ushort4 r;
        r.x = f2bf(v.x); r.y = f2bf(v.y); r.z = f2bf(v.z); r.w = f2bf(v.w);
        *dst = r;
    }
}

__global__ __launch_bounds__(256) void f32_to_bf16_k(const float* __restrict__ in,
                                                     u16* __restrict__ out, int n4) {
    int i = blockIdx.x * 256 + threadIdx.x;
    const int stride = gridDim.x * 256;
    for (; i < n4; i += stride) {
        float4 v = ((const float4*)in)[i];
        ushort4 r;
        r.x = f2bf(v.x); r.y = f2bf(v.y); r.z = f2bf(v.z); r.w = f2bf(v.w);
        ((ushort4*)out)[i] = r;
    }
}

__global__ __launch_bounds__(64) void rope_table(float* __restrict__ ct,
                                                 float* __restrict__ st) {
    const int s = blockIdx.x;
    const int i = threadIdx.x;
    const double invf = pow(5.0e6, -(double)i / 64.0);
    const double ang  = (double)s * invf;
    ct[s * 64 + i] = (float)cos(ang);
    st[s * 64 + i] = (float)sin(ang);
}

// ---------------------------------------------------------------------------
// Output-projection GEMM: round-0 single-buffer structure.
// ---------------------------------------------------------------------------
__global__ __launch_bounds__(256) void gemm_bf16_nt(const __bf16* __restrict__ A,
                                                    const __bf16* __restrict__ B,
                                                    float* __restrict__ C,
                                                    int M, int N, int K) {
    __shared__ __align__(16) __bf16 Als[128 * 64];
    __shared__ __align__(16) __bf16 Bls[128 * 64];
    const int tid  = threadIdx.x;
    const int lane = tid & 63;
    const int wave = tid >> 6;
    const int wm   = wave >> 1, wn = wave & 1;
    const int m0   = blockIdx.y * 128;
    const int n0   = blockIdx.x * 128;
    const int frow = lane & 15;
    const int fkq  = lane >> 4;

    f32x4 acc[4][4];
#pragma unroll
    for (int t = 0; t < 4; ++t)
#pragma unroll
        for (int u = 0; u < 4; ++u)
            acc[t][u] = (f32x4){0.f, 0.f, 0.f, 0.f};

    for (int k0 = 0; k0 < K; k0 += 64) {
        __syncthreads();
#pragma unroll
        for (int i = 0; i < 2; ++i) {
            const int mt  = i * 4 + wave;
            const int row = mt * 16 + frow;
#pragma unroll
            for (int kh = 0; kh < 2; ++kh) {
                const int col = k0 + kh * 32 + fkq * 8;
                load16_to_lds(A + (size_t)(m0 + row) * K + col,
                              &Als[(size_t)((mt * 2 + kh) * 64) * 8]);
                load16_to_lds(B + (size_t)(n0 + row) * K + col,
                              &Bls[(size_t)((mt * 2 + kh) * 64) * 8]);
            }
        }
        __syncthreads();

#pragma unroll
        for (int kh = 0; kh < 2; ++kh) {
            bf16x8 af[4], bfr[4];
#pragma unroll
            for (int t = 0; t < 4; ++t)
                af[t]  = *(const bf16x8*)&Als[(((wm * 4 + t) * 2 + kh) * 64 + lane) * 8];
#pragma unroll
            for (int u = 0; u < 4; ++u)
                bfr[u] = *(const bf16x8*)&Bls[(((wn * 4 + u) * 2 + kh) * 64 + lane) * 8];
#pragma unroll
            for (int t = 0; t < 4; ++t)
#pragma unroll
                for (int u = 0; u < 4; ++u)
                    acc[t][u] = __builtin_amdgcn_mfma_f32_16x16x32_bf16(
                                    af[t], bfr[u], acc[t][u], 0, 0, 0);
        }
    }

    const int crow = (lane >> 4) * 4;
    const int ccol = lane & 15;
#pragma unroll
    for (int t = 0; t < 4; ++t) {
        const int gr = m0 + (wm * 4 + t) * 16 + crow;
#pragma unroll
        for (int u = 0; u < 4; ++u) {
            const int gc = n0 + (wn * 4 + u) * 16 + ccol;
#pragma unroll
            for (int r = 0; r < 4; ++r)
                C[(size_t)(gr + r) * N + gc] = acc[t][u][r];
        }
    }
}

// ---------------------------------------------------------------------------
// 256x256 8-phase QKV GEMM with fused RMSNorm/RoPE/cast/V-transpose epilogue.
// Round-4 change: 3-bit LDS swizzle (was 1-bit: 5.9M residual conflicts).
// ---------------------------------------------------------------------------
__global__ __launch_bounds__(512, 2) void gemm_qkv_8ph(const __bf16* __restrict__ A,
                                                       const __bf16* __restrict__ Bq,
                                                       const __bf16* __restrict__ Bkv,
                                                       const float* __restrict__ ct,
                                                       const float* __restrict__ st,
                                                       const float* __restrict__ qw,
                                                       const float* __restrict__ kw,
                                                       u16*   __restrict__ qrb,
                                                       float* __restrict__ kc,
                                                       u16*   __restrict__ kcb,
                                                       float* __restrict__ vc,
                                                       u16*   __restrict__ vtb) {
    __shared__ __align__(16) __bf16 Als[4][128 * 64];   // [buf*2+half] 64KB
    __shared__ __align__(16) __bf16 Bls[4][128 * 64];   // 64KB

    const int K   = DMODEL;
    const int nkt = K / 64;                  // 40
    const int n0g = blockIdx.x * 256;
    const __bf16* B;
    int n0;
    if (n0g < QKDIM) { B = Bq;  n0 = n0g; }
    else             { B = Bkv; n0 = n0g - QKDIM; }
    const int m0 = blockIdx.y * 256;

    const int tid  = threadIdx.x;
    const int lane = tid & 63;
    const int wave = tid >> 6;
    const int wm   = wave >> 1;              // 0..3: 64-row band
    const int wn   = wave & 1;               // 0..1: 128-col half (one head)
    const int frow = lane & 15;
    const int fkq  = lane >> 4;
    const int ha   = wm >> 1;                // A half this wave reads
    const int ar0  = (wm & 1) * 64 + frow;   // base row within A half

    f32x4 acc[4][8];
#pragma unroll
    for (int t = 0; t < 4; ++t)
#pragma unroll
        for (int u = 0; u < 8; ++u)
            acc[t][u] = (f32x4){0.f, 0.f, 0.f, 0.f};

    // -------- prologue: kt0 (4 halves) + kt1 {A0,B0,B1}; vmcnt(6) => kt0 in
    stage_half(A + (size_t)m0 * K,               K, Als[0], wave, lane);
    stage_half(A + (size_t)(m0 + 128) * K,       K, Als[1], wave, lane);
    stage_half(B + (size_t)n0 * K,               K, Bls[0], wave, lane);
    stage_half(B + (size_t)(n0 + 128) * K,       K, Bls[1], wave, lane);
    stage_half(A + (size_t)m0 * K + 64,          K, Als[2], wave, lane);
    stage_half(B + (size_t)n0 * K + 64,          K, Bls[2], wave, lane);
    stage_half(B + (size_t)(n0 + 128) * K + 64,  K, Bls[3], wave, lane);
    asm volatile("s_waitcnt vmcnt(6)" ::: "memory");
    PHASE_BAR();

    for (int kt = 0; kt < nkt; ++kt) {
        const int bf = kt & 1;
        const __bf16* Ahb = Als[bf * 2 + ha];
        const __bf16* Bhb = Bls[bf * 2 + wn];

        // ================= phase 1: Q(m01, n0-3) =================
        bf16x8 a0[2][2], b0[4][2];
#pragma unroll
        for (int mt = 0; mt < 2; ++mt)
#pragma unroll
            for (int kh = 0; kh < 2; ++kh)
                a0[mt][kh] = *fragp(Ahb, ar0 + mt * 16, kh * 64 + fkq * 16);
#pragma unroll
        for (int nt = 0; nt < 4; ++nt)
#pragma unroll
            for (int kh = 0; kh < 2; ++kh)
                b0[nt][kh] = *fragp(Bhb, nt * 16 + frow, kh * 64 + fkq * 16);
        if (kt + 1 < nkt)
            stage_half(A + (size_t)(m0 + 128) * K + (kt + 1) * 64, K,
                       Als[(bf ^ 1) * 2 + 1], wave, lane);
        asm volatile("s_waitcnt lgkmcnt(8)" ::: "memory");
        PHASE_BAR();
        WAIT_LGKM0();
        __builtin_amdgcn_s_setprio(1);
#pragma unroll
        for (int mt = 0; mt < 2; ++mt)
#pragma unroll
            for (int nt = 0; nt < 4; ++nt)
#pragma unroll
                for (int kh = 0; kh < 2; ++kh)
                    acc[mt][nt] = __builtin_amdgcn_mfma_f32_16x16x32_bf16(
                                      a0[mt][kh], b0[nt][kh], acc[mt][nt], 0, 0, 0);
        __builtin_amdgcn_s_setprio(0);
        PHASE_BAR();

        // ================= phase 2: Q(m23, n0-3) =================
        bf16x8 a1[2][2];
#pragma unroll
        for (int mt = 0; mt < 2; ++mt)
#pragma unroll
            for (int kh = 0; kh < 2; ++kh)
                a1[mt][kh] = *fragp(Ahb, ar0 + 32 + mt * 16, kh * 64 + fkq * 16);
        PHASE_BAR();
        WAIT_LGKM0();
        __builtin_amdgcn_s_setprio(1);
#pragma unroll
        for (int mt = 0; mt < 2; ++mt)
#pragma unroll
            for (int nt = 0; nt < 4; ++nt)
#pragma unroll
                for (int kh = 0; kh < 2; ++kh)
                    acc[2 + mt][nt] = __builtin_amdgcn_mfma_f32_16x16x32_bf16(
                                          a1[mt][kh], b0[nt][kh], acc[2 + mt][nt], 0, 0, 0);
        __builtin_amdgcn_s_setprio(0);
        PHASE_BAR();

        // ================= phase 3: Q(m23, n4-7) =================
        bf16x8 b1[4][2];
#pragma unroll
        for (int nt = 0; nt < 4; ++nt)
#pragma unroll
            for (int kh = 0; kh < 2; ++kh)
                b1[nt][kh] = *fragp(Bhb, (4 + nt) * 16 + frow, kh * 64 + fkq * 16);
        if (kt + 2 < nkt)
            stage_half(A + (size_t)m0 * K + (kt + 2) * 64, K,
                       Als[bf * 2 + 0], wave, lane);
        PHASE_BAR();
        WAIT_LGKM0();
        __builtin_amdgcn_s_setprio(1);
#pragma unroll
        for (int mt = 0; mt < 2; ++mt)
#pragma unroll
            for (int nt = 0; nt < 4; ++nt)
#pragma unroll
                for (int kh = 0; kh < 2; ++kh)
                    acc[2 + mt][4 + nt] = __builtin_amdgcn_mfma_f32_16x16x32_bf16(
                                              a1[mt][kh], b1[nt][kh], acc[2 + mt][4 + nt], 0, 0, 0);
        __builtin_amdgcn_s_setprio(0);
        PHASE_BAR();

        // ================= phase 4: Q(m01, n4-7) =================
        if (kt + 2 < nkt) {
            stage_half(B + (size_t)n0 * K + (kt + 2) * 64,         K,
                       Bls[bf * 2 + 0], wave, lane);
            stage_half(B + (size_t)(n0 + 128) * K + (kt + 2) * 64, K,
                       Bls[bf * 2 + 1], wave, lane);
        }
        PHASE_BAR();
        WAIT_LGKM0();
        __builtin_amdgcn_s_setprio(1);
#pragma unroll
        for (int mt = 0; mt < 2; ++mt)
#pragma unroll
            for (int nt = 0; nt < 4; ++nt)
#pragma unroll
                for (int kh = 0; kh < 2; ++kh)
                    acc[mt][4 + nt] = __builtin_amdgcn_mfma_f32_16x16x32_bf16(
                                          a0[mt][kh], b1[nt][kh], acc[mt][4 + nt], 0, 0, 0);
        __builtin_amdgcn_s_setprio(0);
        if (kt < nkt - 2) asm volatile("s_waitcnt vmcnt(6)" ::: "memory");
        else              asm volatile("s_waitcnt vmcnt(0)" ::: "memory");
        PHASE_BAR();
    }

    // ------------------ fused epilogue (within-wave) ------------------
    const int fr = frow;
    const int fq = fkq;
    const int nw = n0g + wn * 128;
    if (n0g < QKDIM + KVDIM) {
        const int isQ = (n0g < QKDIM) ? 1 : 0;
        const float* w = isQ ? qw : kw;
        float wv[8];
#pragma unroll
        for (int u = 0; u < 8; ++u) wv[u] = w[u * 16 + fr];

#pragma unroll
        for (int mt = 0; mt < 4; ++mt) {
#pragma unroll
            for (int r = 0; r < 4; ++r) {
                float ss = 0.f;
#pragma unroll
                for (int u = 0; u < 8; ++u) ss += acc[mt][u][r] * acc[mt][u][r];
                ss += __shfl_xor(ss, 1);
                ss += __shfl_xor(ss, 2);
                ss += __shfl_xor(ss, 4);
                ss += __shfl_xor(ss, 8);
                const float rstd = rsqrtf(ss * (1.0f / 128.0f) + 1e-6f);
                const int s = m0 + wm * 64 + mt * 16 + fq * 4 + r;
#pragma unroll
                for (int u = 0; u < 4; ++u) {
                    const float cs  = ct[s * 64 + u * 16 + fr];
                    const float sn  = st[s * 64 + u * 16 + fr];
                    const float ylo = acc[mt][u][r]     * rstd * wv[u];
                    const float yhi = acc[mt][u + 4][r] * rstd * wv[u + 4];
                    const float olo = ylo * cs - yhi * sn;
                    const float ohi = yhi * cs + ylo * sn;
                    if (isQ) {
                        const int h = nw >> 7;
                        const size_t base = ((size_t)h * S_LEN + s) * HD;
                        qrb[base + u * 16 + fr]       = f2bf(olo * 0.12751743f);
                        qrb[base + (u + 4) * 16 + fr] = f2bf(ohi * 0.12751743f);
                    } else {
                        const int g = (nw - QKDIM) >> 7;
                        const size_t base = ((size_t)g * S_LEN + s) * HD;
                        kc [base + u * 16 + fr]       = olo;
                        kc [base + (u + 4) * 16 + fr] = ohi;
                        kcb[base + u * 16 + fr]       = f2bf(olo);
                        kcb[base + (u + 4) * 16 + fr] = f2bf(ohi);
                    }
                }
            }
        }
    } else {
        const int g = (nw - QKDIM - KVDIM) >> 7;
#pragma unroll
        for (int mt = 0; mt < 4; ++mt) {
            const int sb = m0 + wm * 64 + mt * 16 + fq * 4;   // 4 consecutive s
#pragma unroll
            for (int u = 0; u < 8; ++u) {
                const int d = u * 16 + fr;
                ushort4 o;
                o.x = f2bf(acc[mt][u][0]); o.y = f2bf(acc[mt][u][1]);
                o.z = f2bf(acc[mt][u][2]); o.w = f2bf(acc[mt][u][3]);
                *(ushort4*)&vtb[((size_t)g * HD + d) * S_LEN + sb] = o;
#pragma unroll
                for (int r = 0; r < 4; ++r)
                    vc[((size_t)g * S_LEN + sb + r) * HD + d] = acc[mt][u][r];
            }
        }
    }
}

// ---------------------------------------------------------------------------
// Flash attention, round 4: SWAPPED QK^T + fully in-register softmax.
// sT[u] = mfma(K_frag, Q_frag): lane holds S[k = u*16+fq*4+r][m = fr] --
// the whole k-row group for ONE q-column lives in the 4-lane fq-group:
// row-reduce = 15 reg-max + 2 shfl (was 32 shfl). P -> PV A-fragment via
// 8 v_cvt_pk_bf16_f32 + 16 shfl + 8 cndmask in-register (P LDS deleted,
// 2.16M bank-conflict cycles -> 0). Defer-max THR=8 (T13) skips the
// 32-mul rescale on most tiles. Causal pairing + async dbuf kept.
// LDS: K dbuf 32KB + V dbuf 32KB = 64KB -> 2 blocks/CU.
// ---------------------------------------------------------------------------
__device__ __forceinline__ void attn_tile_swapped(
        const bf16x8 aq[4], f32x4 o_acc[8], float& m_i, float& l_i,
        const __bf16* __restrict__ Kl, const __bf16* __restrict__ Vl,
        int lane, int fr, int fq, int qm, int kbase, bool diag) {
    // ---- QK^T, swapped: S^T[k][m] ----
    f32x4 sT[4];
#pragma unroll
    for (int u = 0; u < 4; ++u) sT[u] = (f32x4){0.f, 0.f, 0.f, 0.f};
    __builtin_amdgcn_s_setprio(1);
#pragma unroll
    for (int u = 0; u < 4; ++u)
#pragma unroll
        for (int ks = 0; ks < 4; ++ks)
            sT[u] = __builtin_amdgcn_mfma_f32_16x16x32_bf16(
                        *(const bf16x8*)&Kl[((u * 4 + ks) * 64 + lane) * 8],
                        aq[ks], sT[u], 0, 0, 0);
    __builtin_amdgcn_s_setprio(0);

    // ---- causal mask (diag tile): k > q ----
    if (diag) {
#pragma unroll
        for (int u = 0; u < 4; ++u)
#pragma unroll
            for (int r = 0; r < 4; ++r)
                if (kbase + u * 16 + fq * 4 + r > qm + fr)
                    sT[u][r] = -INFINITY;
    }

    // ---- row max: 15 reg-max + 2 shfl across fq-group ----
    float mx = sT[0][0];
#pragma unroll
    for (int u = 0; u < 4; ++u)
#pragma unroll
        for (int r = 0; r < 4; ++r) mx = fmaxf(mx, sT[u][r]);
    mx = fmaxf(mx, __shfl_xor(mx, 16));
    mx = fmaxf(mx, __shfl_xor(mx, 32));

    // ---- defer-max (T13, THR=8): rescale only when max grew enough ----
    if (__any(mx > m_i + 8.0f)) {
        const float m_new = fmaxf(m_i, mx);
        const float alpha = exp2f(m_i - m_new);
        m_i = m_new;
        l_i *= alpha;
#pragma unroll
        for (int r = 0; r < 4; ++r) {
            const float a = __shfl(alpha, fq * 4 + r);  // alpha of o-row m=fq*4+r
#pragma unroll
            for (int dt = 0; dt < 8; ++dt) o_acc[dt][r] *= a;
        }
    }

    // ---- P = 2^(s - m), row-sum ----
    float p[4][4];
    float ps = 0.f;
#pragma unroll
    for (int u = 0; u < 4; ++u)
#pragma unroll
        for (int r = 0; r < 4; ++r) {
            p[u][r] = exp2f(sT[u][r] - m_i);
            ps += p[u][r];
        }
    ps += __shfl_xor(ps, 16);
    ps += __shfl_xor(ps, 32);
    l_i += ps;

    // ---- pack pairs: pk[u][h] = {bf16(p[u][2h]), bf16(p[u][2h+1])} ----
    unsigned pk[4][2];
#pragma unroll
    for (int u = 0; u < 4; ++u)
#pragma unroll
        for (int hh = 0; hh < 2; ++hh)
            asm("v_cvt_pk_bf16_f32 %0, %1, %2"
                : "=v"(pk[u][hh]) : "v"(p[u][2 * hh]), "v"(p[u][2 * hh + 1]));

    // ---- in-register transpose to PV A-fragments (4-lane fq-group) ----
    // target word (ks,jp) needs k = ks*32 + fq*8 + 2jp+{0,1} of column m=fr:
    // src lane = fr + 16*((fq&1)*2 + (jp>>1)), src word = pk[2ks+(fq>>1)][jp&1]
    const int slA = fr + 16 * ((fq & 1) * 2);
    const int slB = slA + 16;
    bf16x8 ap[2];
#pragma unroll
    for (int ks = 0; ks < 2; ++ks) {
        unsigned w[4];
#pragma unroll
        for (int jp = 0; jp < 4; ++jp) {
            const int sl = (jp & 2) ? slB : slA;
            const unsigned v0 = (unsigned)__shfl((int)pk[2 * ks + 0][jp & 1], sl);
            const unsigned v1 = (unsigned)__shfl((int)pk[2 * ks + 1][jp & 1], sl);
            w[jp] = (fq & 2) ? v1 : v0;
        }
        ap[ks] = __builtin_bit_cast(bf16x8, (uint4){w[0], w[1], w[2], w[3]});
    }

    // ---- PV ----
    __builtin_amdgcn_s_setprio(1);
#pragma unroll
    for (int dt = 0; dt < 8; ++dt)
#pragma unroll
        for (int ks = 0; ks < 2; ++ks)
            o_acc[dt] = __builtin_amdgcn_mfma_f32_16x16x32_bf16(
                            ap[ks],
                            *(const bf16x8*)&Vl[((dt * 2 + ks) * 64 + lane) * 8],
                            o_acc[dt], 0, 0, 0);
    __builtin_amdgcn_s_setprio(0);
}

__global__ __launch_bounds__(256, 2) void attn_mfma(const __bf16* __restrict__ Qb,
                                                    const __bf16* __restrict__ Kb,
                                                    const __bf16* __restrict__ Vt,
                                                    u16* __restrict__ Ob) {
    __shared__ __align__(16) __bf16 Kls[2][16 * 64 * 8];  // 2 x 16KB
    __shared__ __align__(16) __bf16 Vls[2][16 * 64 * 8];  // 2 x 16KB

    const int h    = blockIdx.x;
    const int g    = h >> 2;
    const int pair = blockIdx.y;                 // 0..15
    const int ytl  = pair;                       // low q-tile
    const int yth  = (S_LEN / 64 - 1) - pair;    // high q-tile
    const int q0l  = ytl * 64;
    const int q0h  = yth * 64;
    const int tid  = threadIdx.x;
    const int lane = tid & 63;
    const int wave = tid >> 6;
    const int fr   = lane & 15;
    const int fq   = lane >> 4;

    // stage both Q tiles (hi -> Kls[0], lo -> Kls[1]), hoist to regs
    {
        const __bf16* Qh = Qb + ((size_t)h * S_LEN + q0h + wave * 16 + fr) * HD;
        const __bf16* Ql = Qb + ((size_t)h * S_LEN + q0l + wave * 16 + fr) * HD;
#pragma unroll
        for (int ks = 0; ks < 4; ++ks) {
            load16_to_lds(Qh + ks * 32 + fq * 8, &Kls[0][(size_t)((wave * 4 + ks) * 64) * 8]);
            load16_to_lds(Ql + ks * 32 + fq * 8, &Kls[1][(size_t)((wave * 4 + ks) * 64) * 8]);
        }
    }
    __syncthreads();
    bf16x8 aqh[4], aql[4];
#pragma unroll
    for (int ks = 0; ks < 4; ++ks) {
        aqh[ks] = *(const bf16x8*)&Kls[0][((wave * 4 + ks) * 64 + lane) * 8];
        aql[ks] = *(const bf16x8*)&Kls[1][((wave * 4 + ks) * 64 + lane) * 8];
    }
    __syncthreads();   // reg hoist complete before Kls reused for K

    float m_h = -INFINITY, l_h = 0.f, m_l = -INFINITY, l_l = 0.f;
    f32x4 o_h[8], o_l[8];
#pragma unroll
    for (int dt = 0; dt < 8; ++dt) {
        o_h[dt] = (f32x4){0.f, 0.f, 0.f, 0.f};
        o_l[dt] = (f32x4){0.f, 0.f, 0.f, 0.f};
    }

    // stage kt=0
    {
        const __bf16* Kg = Kb + ((size_t)g * S_LEN + wave * 16 + fr) * HD;
#pragma unroll
        for (int ks = 0; ks < 4; ++ks)
            load16_to_lds(Kg + ks * 32 + fq * 8, &Kls[0][(size_t)((wave * 4 + ks) * 64) * 8]);
#pragma unroll
        for (int i = 0; i < 2; ++i) {
            const int dt = wave * 2 + i;
            const __bf16* Vg = Vt + ((size_t)g * HD + dt * 16 + fr) * S_LEN;
#pragma unroll
            for (int ks = 0; ks < 2; ++ks)
                load16_to_lds(Vg + ks * 32 + fq * 8, &Vls[0][(size_t)((dt * 2 + ks) * 64) * 8]);
        }
    }
    __syncthreads();   // kt=0 staged

    for (int kt = 0; kt <= yth; ++kt) {
        const int buf = kt & 1;
        // issue next tile's stage into the other buffer (hidden under compute)
        if (kt < yth) {
            const int nb = buf ^ 1;
            const __bf16* Kg = Kb + ((size_t)g * S_LEN + (kt + 1) * 64 + wave * 16 + fr) * HD;
#pragma unroll
            for (int ks = 0; ks < 4; ++ks)
                load16_to_lds(Kg + ks * 32 + fq * 8, &Kls[nb][(size_t)((wave * 4 + ks) * 64) * 8]);
#pragma unroll
            for (int i = 0; i < 2; ++i) {
                const int dt = wave * 2 + i;
                const __bf16* Vg = Vt + ((size_t)g * HD + dt * 16 + fr) * S_LEN + (kt + 1) * 64;
#pragma unroll
                for (int ks = 0; ks < 2; ++ks)
                    load16_to_lds(Vg + ks * 32 + fq * 8, &Vls[nb][(size_t)((dt * 2 + ks) * 64) * 8]);
            }
        }

        // high q-tile: always active
        attn_tile_swapped(aqh, o_h, m_h, l_h, Kls[buf], Vls[buf],
                          lane, fr, fq, q0h + wave * 16, kt * 64, kt == yth);
        // low q-tile: active while kt <= ytl
        if (kt <= ytl)
            attn_tile_swapped(aql, o_l, m_l, l_l, Kls[buf], Vls[buf],
                              lane, fr, fq, q0l + wave * 16, kt * 64, kt == ytl);

        __syncthreads();   // drains vmcnt (next buf staged) + LDS reuse safe
    }

    // ---- epilogue: both tiles (l per column m=fr -> shfl to o-row m) ----
#pragma unroll
    for (int r = 0; r < 4; ++r) {
        const float ih = 1.0f / __shfl(l_h, fq * 4 + r);
        const float il = 1.0f / __shfl(l_l, fq * 4 + r);
        const int sh = q0h + wave * 16 + fq * 4 + r;
        const int sl = q0l + wave * 16 + fq * 4 + r;
#pragma unroll
        for (int dt = 0; dt < 8; ++dt) {
            Ob[(size_t)sh * QKDIM + h * HD + dt * 16 + fr] = f2bf(o_h[dt][r] * ih);
            Ob[(size_t)sl * QKDIM + h * HD + dt * 16 + fr] = f2bf(o_l[dt][r] * il);
        }
    }
}

// ---------------------------------------------------------------------------
extern "C" void kernel_launch(void* const* d_in, const int* in_sizes, int n_in,
                              void* d_out, int out_size, void* d_ws, size_t ws_size,
                              hipStream_t stream) {
    const float* x  = (const float*)d_in[0];
    const float* Wq = (const float*)d_in[1];
    const float* Wk = (const float*)d_in[2];
    const float* Wv = (const float*)d_in[3];
    const float* Wo = (const float*)d_in[4];
    const float* qw = (const float*)d_in[5];
    const float* kw = (const float*)d_in[6];

    float* out     = (float*)d_out;
    float* cache_k = out + (size_t)S_LEN * DMODEL;
    float* cache_v = cache_k + (size_t)NKV * S_LEN * HD;

    // ---- workspace layout (u16 units from base) ----
    u16* wsu = (u16*)d_ws;
    u16* qrb = wsu;
    u16* kcb = qrb + (size_t)NHEADS * S_LEN * HD;
    u16* vtb = kcb + (size_t)NKV * S_LEN * HD;
    u16* Wqb = vtb + (size_t)NKV * S_LEN * HD;
    u16* Wkb = Wqb + (size_t)QKDIM * DMODEL;
    u16* aob = Wqb;                               // overlay (weights dead)
    u16* Wob = aob + (size_t)S_LEN * QKDIM;
    float* ct = (float*)(Wqb + (size_t)S_LEN * QKDIM + (size_t)DMODEL * QKDIM);
    float* st = ct + S_LEN * 64;
    u16* xb  = (u16*)out;                         // x bf16 in out region

    // 1) input converts + rope tables
    convert_inputs<<<4096, 256, 0, stream>>>(x, Wq, Wk, Wv, xb, Wqb);
    rope_table<<<S_LEN, 64, 0, stream>>>(ct, st);

    // 2) 8-phase fused QKV projection + RMSNorm + RoPE + casts + V transpose
    gemm_qkv_8ph<<<dim3((QKDIM + 2 * KVDIM) / 256, S_LEN / 256), 512, 0, stream>>>(
        (const __bf16*)xb, (const __bf16*)Wqb, (const __bf16*)Wkb,
        ct, st, qw, kw, qrb, cache_k, kcb, cache_v, vtb);

    // 3) Wo convert + attention (swapped-QK^T in-register softmax)
    f32_to_bf16_k<<<1024, 256, 0, stream>>>(Wo, Wob, DMODEL * QKDIM / 4);
    attn_mfma<<<dim3(NHEADS, S_LEN / 128), 256, 0, stream>>>(
        (const __bf16*)qrb, (const __bf16*)kcb, (const __bf16*)vtb, aob);

    // 4) output projection (round-0 single-buffer structure)
    gemm_bf16_nt<<<dim3(DMODEL / 128, S_LEN / 128), 256, 0, stream>>>(
        (const __bf16*)aob, (const __bf16*)Wob, out, S_LEN, DMODEL, QKDIM);
}

// Round 5
// 422.693 us; speedup vs baseline: 1.3950x; 1.0764x over previous
//
#include <hip/hip_runtime.h>
#include <hip/hip_bf16.h>
#include <math.h>

#define S_LEN  2048
#define DMODEL 2560
#define NHEADS 32
#define NKV    8
#define HD     128
#define QKDIM  (NHEADS * HD)   // 4096
#define KVDIM  (NKV * HD)      // 1024

typedef __bf16 bf16x8 __attribute__((ext_vector_type(8)));
typedef float  f32x4  __attribute__((ext_vector_type(4)));
typedef unsigned short u16;

#define AS1 __attribute__((address_space(1)))
#define AS3 __attribute__((address_space(3)))

__device__ __forceinline__ void load16_to_lds(const void* g, void* l) {
    __builtin_amdgcn_global_load_lds((const AS1 void*)g, (AS3 void*)l, 16, 0, 0);
}

__device__ __forceinline__ u16 f2bf(float f) {
    unsigned u = __builtin_bit_cast(unsigned, f);
    return (u16)((u + 0x7fff + ((u >> 16) & 1)) >> 16);   // RTNE
}

// phase-boundary helpers (raw s_barrier; sched_barrier pins ds_reads, rule #18)
#define PHASE_BAR() do { __builtin_amdgcn_sched_barrier(0);            \
                         __builtin_amdgcn_s_barrier();                 \
                         __builtin_amdgcn_sched_barrier(0); } while (0)
#define WAIT_LGKM0() do { asm volatile("s_waitcnt lgkmcnt(0)" ::: "memory"); \
                          __builtin_amdgcn_sched_barrier(0); } while (0)

// LDS XOR-swizzle, 3-bit (G4-verified): byte ^= ((row&7)<<4) for a
// [128 rows][64 cols] bf16 half-tile (row pitch 128B).
__device__ __forceinline__ const bf16x8* fragp(const __bf16* hbase, int row, int colb) {
    int b = (row << 7) | colb;
    b ^= ((b >> 7) & 7) << 4;
    return (const bf16x8*)((const char*)hbase + b);
}

// Staging: global_load_lds writes LINEARLY; swizzle applied by pre-swizzling
// the per-lane GLOBAL source address (same involution).
__device__ __forceinline__ void stage_half(const __bf16* __restrict__ g0, int Kp,
                                           __bf16* l0, int wave, int lane) {
#pragma unroll
    for (int j = 0; j < 2; ++j) {
        const int p = ((wave * 2 + j) << 10) | (lane << 4);   // physical byte
        const int b = p ^ (((p >> 7) & 7) << 4);              // logical byte
        load16_to_lds((const char*)g0 + (size_t)(b >> 7) * (Kp * 2) + (b & 127),
                      (char*)l0 + ((wave * 2 + j) << 10));
    }
}

// ---------------------------------------------------------------------------
// Fused input convert: x | Wq | Wk | Wv -> bf16 in one launch.
// ---------------------------------------------------------------------------
#define N4_X   (S_LEN * DMODEL / 4)
#define N4_WQ  (QKDIM * DMODEL / 4)
#define N4_WK  (KVDIM * DMODEL / 4)
#define N4_ALL (N4_X + N4_WQ + 2 * N4_WK)

__global__ __launch_bounds__(256) void convert_inputs(const float* __restrict__ x,
                                                      const float* __restrict__ wq,
                                                      const float* __restrict__ wk,
                                                      const float* __restrict__ wv,
                                                      u16* __restrict__ xb,
                                                      u16* __restrict__ wb) {
    const int stride = gridDim.x * 256;
    for (int i = blockIdx.x * 256 + threadIdx.x; i < N4_ALL; i += stride) {
        const float4* src;
        ushort4* dst;
        if (i < N4_X) {
            src = (const float4*)x + i;
            dst = (ushort4*)xb + i;
        } else {
            const int j = i - N4_X;
            dst = (ushort4*)wb + j;
            if (j < N4_WQ)                  src = (const float4*)wq + j;
            else if (j < N4_WQ + N4_WK)     src = (const float4*)wk + (j - N4_WQ);
            else                            src = (const float4*)wv + (j - N4_WQ - N4_WK);
        }
        float4 v = *src;
        ushort4 r;
        r.x = f2bf(v.x); r.y = f2bf(v.y); r.z = f2bf(v.z); r.w = f2bf(v.w);
        *dst = r;
    }
}

// ---------------------------------------------------------------------------
// Prep for out-projection: zero the out accumulator (atomic split-K target)
// and convert Wo -> bf16. Must run AFTER gemm_qkv (xb overlays out region).
// ---------------------------------------------------------------------------
#define N4_OUT (S_LEN * DMODEL / 4)     // 1310720
#define N4_WO  (DMODEL * QKDIM / 4)     // 2621440

__global__ __launch_bounds__(256) void prep_outproj(const float* __restrict__ wo,
                                                    u16* __restrict__ wob,
                                                    float* __restrict__ outz) {
    const int stride = gridDim.x * 256;
    for (int i = blockIdx.x * 256 + threadIdx.x; i < N4_OUT + N4_WO; i += stride) {
        if (i < N4_OUT) {
            ((float4*)outz)[i] = (float4){0.f, 0.f, 0.f, 0.f};
        } else {
            const int j = i - N4_OUT;
            float4 v = ((const float4*)wo)[j];
            ushort4 r;
            r.x = f2bf(v.x); r.y = f2bf(v.y); r.z = f2bf(v.z); r.w = f2bf(v.w);
            ((ushort4*)wob)[j] = r;
        }
    }
}

__global__ __launch_bounds__(64) void rope_table(float* __restrict__ ct,
                                                 float* __restrict__ st) {
    const int s = blockIdx.x;
    const int i = threadIdx.x;
    const double invf = pow(5.0e6, -(double)i / 64.0);
    const double ang  = (double)s * invf;
    ct[s * 64 + i] = (float)cos(ang);
    st[s * 64 + i] = (float)sin(ang);
}

// ---------------------------------------------------------------------------
// 256x256 8-phase QKV GEMM with fused RMSNorm/RoPE/cast/V-transpose epilogue.
// (verified rounds 2-4; 3-bit swizzle)
// ---------------------------------------------------------------------------
__global__ __launch_bounds__(512, 2) void gemm_qkv_8ph(const __bf16* __restrict__ A,
                                                       const __bf16* __restrict__ Bq,
                                                       const __bf16* __restrict__ Bkv,
                                                       const float* __restrict__ ct,
                                                       const float* __restrict__ st,
                                                       const float* __restrict__ qw,
                                                       const float* __restrict__ kw,
                                                       u16*   __restrict__ qrb,
                                                       float* __restrict__ kc,
                                                       u16*   __restrict__ kcb,
                                                       float* __restrict__ vc,
                                                       u16*   __restrict__ vtb) {
    __shared__ __align__(16) __bf16 Als[4][128 * 64];   // [buf*2+half] 64KB
    __shared__ __align__(16) __bf16 Bls[4][128 * 64];   // 64KB

    const int K   = DMODEL;
    const int nkt = K / 64;                  // 40
    const int n0g = blockIdx.x * 256;
    const __bf16* B;
    int n0;
    if (n0g < QKDIM) { B = Bq;  n0 = n0g; }
    else             { B = Bkv; n0 = n0g - QKDIM; }
    const int m0 = blockIdx.y * 256;

    const int tid  = threadIdx.x;
    const int lane = tid & 63;
    const int wave = tid >> 6;
    const int wm   = wave >> 1;              // 0..3: 64-row band
    const int wn   = wave & 1;               // 0..1: 128-col half (one head)
    const int frow = lane & 15;
    const int fkq  = lane >> 4;
    const int ha   = wm >> 1;                // A half this wave reads
    const int ar0  = (wm & 1) * 64 + frow;   // base row within A half

    f32x4 acc[4][8];
#pragma unroll
    for (int t = 0; t < 4; ++t)
#pragma unroll
        for (int u = 0; u < 8; ++u)
            acc[t][u] = (f32x4){0.f, 0.f, 0.f, 0.f};

    // -------- prologue: kt0 (4 halves) + kt1 {A0,B0,B1}; vmcnt(6) => kt0 in
    stage_half(A + (size_t)m0 * K,               K, Als[0], wave, lane);
    stage_half(A + (size_t)(m0 + 128) * K,       K, Als[1], wave, lane);
    stage_half(B + (size_t)n0 * K,               K, Bls[0], wave, lane);
    stage_half(B + (size_t)(n0 + 128) * K,       K, Bls[1], wave, lane);
    stage_half(A + (size_t)m0 * K + 64,          K, Als[2], wave, lane);
    stage_half(B + (size_t)n0 * K + 64,          K, Bls[2], wave, lane);
    stage_half(B + (size_t)(n0 + 128) * K + 64,  K, Bls[3], wave, lane);
    asm volatile("s_waitcnt vmcnt(6)" ::: "memory");
    PHASE_BAR();

    for (int kt = 0; kt < nkt; ++kt) {
        const int bf = kt & 1;
        const __bf16* Ahb = Als[bf * 2 + ha];
        const __bf16* Bhb = Bls[bf * 2 + wn];

        // ================= phase 1: Q(m01, n0-3) =================
        bf16x8 a0[2][2], b0[4][2];
#pragma unroll
        for (int mt = 0; mt < 2; ++mt)
#pragma unroll
            for (int kh = 0; kh < 2; ++kh)
                a0[mt][kh] = *fragp(Ahb, ar0 + mt * 16, kh * 64 + fkq * 16);
#pragma unroll
        for (int nt = 0; nt < 4; ++nt)
#pragma unroll
            for (int kh = 0; kh < 2; ++kh)
                b0[nt][kh] = *fragp(Bhb, nt * 16 + frow, kh * 64 + fkq * 16);
        if (kt + 1 < nkt)
            stage_half(A + (size_t)(m0 + 128) * K + (kt + 1) * 64, K,
                       Als[(bf ^ 1) * 2 + 1], wave, lane);
        asm volatile("s_waitcnt lgkmcnt(8)" ::: "memory");
        PHASE_BAR();
        WAIT_LGKM0();
        __builtin_amdgcn_s_setprio(1);
#pragma unroll
        for (int mt = 0; mt < 2; ++mt)
#pragma unroll
            for (int nt = 0; nt < 4; ++nt)
#pragma unroll
                for (int kh = 0; kh < 2; ++kh)
                    acc[mt][nt] = __builtin_amdgcn_mfma_f32_16x16x32_bf16(
                                      a0[mt][kh], b0[nt][kh], acc[mt][nt], 0, 0, 0);
        __builtin_amdgcn_s_setprio(0);
        PHASE_BAR();

        // ================= phase 2: Q(m23, n0-3) =================
        bf16x8 a1[2][2];
#pragma unroll
        for (int mt = 0; mt < 2; ++mt)
#pragma unroll
            for (int kh = 0; kh < 2; ++kh)
                a1[mt][kh] = *fragp(Ahb, ar0 + 32 + mt * 16, kh * 64 + fkq * 16);
        PHASE_BAR();
        WAIT_LGKM0();
        __builtin_amdgcn_s_setprio(1);
#pragma unroll
        for (int mt = 0; mt < 2; ++mt)
#pragma unroll
            for (int nt = 0; nt < 4; ++nt)
#pragma unroll
                for (int kh = 0; kh < 2; ++kh)
                    acc[2 + mt][nt] = __builtin_amdgcn_mfma_f32_16x16x32_bf16(
                                          a1[mt][kh], b0[nt][kh], acc[2 + mt][nt], 0, 0, 0);
        __builtin_amdgcn_s_setprio(0);
        PHASE_BAR();

        // ================= phase 3: Q(m23, n4-7) =================
        bf16x8 b1[4][2];
#pragma unroll
        for (int nt = 0; nt < 4; ++nt)
#pragma unroll
            for (int kh = 0; kh < 2; ++kh)
                b1[nt][kh] = *fragp(Bhb, (4 + nt) * 16 + frow, kh * 64 + fkq * 16);
        if (kt + 2 < nkt)
            stage_half(A + (size_t)m0 * K + (kt + 2) * 64, K,
                       Als[bf * 2 + 0], wave, lane);
        PHASE_BAR();
        WAIT_LGKM0();
        __builtin_amdgcn_s_setprio(1);
#pragma unroll
        for (int mt = 0; mt < 2; ++mt)
#pragma unroll
            for (int nt = 0; nt < 4; ++nt)
#pragma unroll
                for (int kh = 0; kh < 2; ++kh)
                    acc[2 + mt][4 + nt] = __builtin_amdgcn_mfma_f32_16x16x32_bf16(
                                              a1[mt][kh], b1[nt][kh], acc[2 + mt][4 + nt], 0, 0, 0);
        __builtin_amdgcn_s_setprio(0);
        PHASE_BAR();

        // ================= phase 4: Q(m01, n4-7) =================
        if (kt + 2 < nkt) {
            stage_half(B + (size_t)n0 * K + (kt + 2) * 64,         K,
                       Bls[bf * 2 + 0], wave, lane);
            stage_half(B + (size_t)(n0 + 128) * K + (kt + 2) * 64, K,
                       Bls[bf * 2 + 1], wave, lane);
        }
        PHASE_BAR();
        WAIT_LGKM0();
        __builtin_amdgcn_s_setprio(1);
#pragma unroll
        for (int mt = 0; mt < 2; ++mt)
#pragma unroll
            for (int nt = 0; nt < 4; ++nt)
#pragma unroll
                for (int kh = 0; kh < 2; ++kh)
                    acc[mt][4 + nt] = __builtin_amdgcn_mfma_f32_16x16x32_bf16(
                                          a0[mt][kh], b1[nt][kh], acc[mt][4 + nt], 0, 0, 0);
        __builtin_amdgcn_s_setprio(0);
        if (kt < nkt - 2) asm volatile("s_waitcnt vmcnt(6)" ::: "memory");
        else              asm volatile("s_waitcnt vmcnt(0)" ::: "memory");
        PHASE_BAR();
    }

    // ------------------ fused epilogue (within-wave) ------------------
    const int fr = frow;
    const int fq = fkq;
    const int nw = n0g + wn * 128;
    if (n0g < QKDIM + KVDIM) {
        const int isQ = (n0g < QKDIM) ? 1 : 0;
        const float* w = isQ ? qw : kw;
        float wv[8];
#pragma unroll
        for (int u = 0; u < 8; ++u) wv[u] = w[u * 16 + fr];

#pragma unroll
        for (int mt = 0; mt < 4; ++mt) {
#pragma unroll
            for (int r = 0; r < 4; ++r) {
                float ss = 0.f;
#pragma unroll
                for (int u = 0; u < 8; ++u) ss += acc[mt][u][r] * acc[mt][u][r];
                ss += __shfl_xor(ss, 1);
                ss += __shfl_xor(ss, 2);
                ss += __shfl_xor(ss, 4);
                ss += __shfl_xor(ss, 8);
                const float rstd = rsqrtf(ss * (1.0f / 128.0f) + 1e-6f);
                const int s = m0 + wm * 64 + mt * 16 + fq * 4 + r;
#pragma unroll
                for (int u = 0; u < 4; ++u) {
                    const float cs  = ct[s * 64 + u * 16 + fr];
                    const float sn  = st[s * 64 + u * 16 + fr];
                    const float ylo = acc[mt][u][r]     * rstd * wv[u];
                    const float yhi = acc[mt][u + 4][r] * rstd * wv[u + 4];
                    const float olo = ylo * cs - yhi * sn;
                    const float ohi = yhi * cs + ylo * sn;
                    if (isQ) {
                        const int h = nw >> 7;
                        const size_t base = ((size_t)h * S_LEN + s) * HD;
                        qrb[base + u * 16 + fr]       = f2bf(olo * 0.12751743f);
                        qrb[base + (u + 4) * 16 + fr] = f2bf(ohi * 0.12751743f);
                    } else {
                        const int g = (nw - QKDIM) >> 7;
                        const size_t base = ((size_t)g * S_LEN + s) * HD;
                        kc [base + u * 16 + fr]       = olo;
                        kc [base + (u + 4) * 16 + fr] = ohi;
                        kcb[base + u * 16 + fr]       = f2bf(olo);
                        kcb[base + (u + 4) * 16 + fr] = f2bf(ohi);
                    }
                }
            }
        }
    } else {
        const int g = (nw - QKDIM - KVDIM) >> 7;
#pragma unroll
        for (int mt = 0; mt < 4; ++mt) {
            const int sb = m0 + wm * 64 + mt * 16 + fq * 4;   // 4 consecutive s
#pragma unroll
            for (int u = 0; u < 8; ++u) {
                const int d = u * 16 + fr;
                ushort4 o;
                o.x = f2bf(acc[mt][u][0]); o.y = f2bf(acc[mt][u][1]);
                o.z = f2bf(acc[mt][u][2]); o.w = f2bf(acc[mt][u][3]);
                *(ushort4*)&vtb[((size_t)g * HD + d) * S_LEN + sb] = o;
#pragma unroll
                for (int r = 0; r < 4; ++r)
                    vc[((size_t)g * S_LEN + sb + r) * HD + d] = acc[mt][u][r];
            }
        }
    }
}

// ---------------------------------------------------------------------------
// Output projection, round 5: 256x256 8-phase + SPLIT-K x3 (22+21+21 K-tiles)
// with atomic f32 accumulation into the pre-zeroed out buffer.
// Grid (10, 8, 3) = 240 blocks ~= 94% CU coverage at 1 block/CU (128KB LDS)
// -- fixes the 320-block/13%-occupancy latency wall of the 128^2 structure.
// ---------------------------------------------------------------------------
__global__ __launch_bounds__(512, 2) void gemm_out_8ph(const __bf16* __restrict__ A,
                                                       const __bf16* __restrict__ B,
                                                       float* __restrict__ C) {
    __shared__ __align__(16) __bf16 Als[4][128 * 64];   // 64KB
    __shared__ __align__(16) __bf16 Bls[4][128 * 64];   // 64KB

    const int K   = QKDIM;                   // 4096
    const int z   = blockIdx.z;
    const int ks0 = (z == 0) ? 0 : 22 + (z - 1) * 21;
    const int L   = (z == 0) ? 22 : 21;      // local K-tile count
    const int ko0 = ks0 * 64;
    const int n0  = blockIdx.x * 256;
    const int m0  = blockIdx.y * 256;

    const int tid  = threadIdx.x;
    const int lane = tid & 63;
    const int wave = tid >> 6;
    const int wm   = wave >> 1;
    const int wn   = wave & 1;
    const int frow = lane & 15;
    const int fkq  = lane >> 4;
    const int ha   = wm >> 1;
    const int ar0  = (wm & 1) * 64 + frow;

    f32x4 acc[4][8];
#pragma unroll
    for (int t = 0; t < 4; ++t)
#pragma unroll
        for (int u = 0; u < 8; ++u)
            acc[t][u] = (f32x4){0.f, 0.f, 0.f, 0.f};

    // prologue: tile ks0 (4 halves) + ks0+1 {A0,B0,B1}; vmcnt(6) => ks0 in
    stage_half(A + (size_t)m0 * K + ko0,              K, Als[0], wave, lane);
    stage_half(A + (size_t)(m0 + 128) * K + ko0,      K, Als[1], wave, lane);
    stage_half(B + (size_t)n0 * K + ko0,              K, Bls[0], wave, lane);
    stage_half(B + (size_t)(n0 + 128) * K + ko0,      K, Bls[1], wave, lane);
    stage_half(A + (size_t)m0 * K + ko0 + 64,         K, Als[2], wave, lane);
    stage_half(B + (size_t)n0 * K + ko0 + 64,         K, Bls[2], wave, lane);
    stage_half(B + (size_t)(n0 + 128) * K + ko0 + 64, K, Bls[3], wave, lane);
    asm volatile("s_waitcnt vmcnt(6)" ::: "memory");
    PHASE_BAR();

    for (int j = 0; j < L; ++j) {
        const int bf = j & 1;
        const __bf16* Ahb = Als[bf * 2 + ha];
        const __bf16* Bhb = Bls[bf * 2 + wn];

        // ================= phase 1 =================
        bf16x8 a0[2][2], b0[4][2];
#pragma unroll
        for (int mt = 0; mt < 2; ++mt)
#pragma unroll
            for (int kh = 0; kh < 2; ++kh)
                a0[mt][kh] = *fragp(Ahb, ar0 + mt * 16, kh * 64 + fkq * 16);
#pragma unroll
        for (int nt = 0; nt < 4; ++nt)
#pragma unroll
            for (int kh = 0; kh < 2; ++kh)
                b0[nt][kh] = *fragp(Bhb, nt * 16 + frow, kh * 64 + fkq * 16);
        if (j + 1 < L)
            stage_half(A + (size_t)(m0 + 128) * K + ko0 + (j + 1) * 64, K,
                       Als[(bf ^ 1) * 2 + 1], wave, lane);
        asm volatile("s_waitcnt lgkmcnt(8)" ::: "memory");
        PHASE_BAR();
        WAIT_LGKM0();
        __builtin_amdgcn_s_setprio(1);
#pragma unroll
        for (int mt = 0; mt < 2; ++mt)
#pragma unroll
            for (int nt = 0; nt < 4; ++nt)
#pragma unroll
                for (int kh = 0; kh < 2; ++kh)
                    acc[mt][nt] = __builtin_amdgcn_mfma_f32_16x16x32_bf16(
                                      a0[mt][kh], b0[nt][kh], acc[mt][nt], 0, 0, 0);
        __builtin_amdgcn_s_setprio(0);
        PHASE_BAR();

        // ================= phase 2 =================
        bf16x8 a1[2][2];
#pragma unroll
        for (int mt = 0; mt < 2; ++mt)
#pragma unroll
            for (int kh = 0; kh < 2; ++kh)
                a1[mt][kh] = *fragp(Ahb, ar0 + 32 + mt * 16, kh * 64 + fkq * 16);
        PHASE_BAR();
        WAIT_LGKM0();
        __builtin_amdgcn_s_setprio(1);
#pragma unroll
        for (int mt = 0; mt < 2; ++mt)
#pragma unroll
            for (int nt = 0; nt < 4; ++nt)
#pragma unroll
                for (int kh = 0; kh < 2; ++kh)
                    acc[2 + mt][nt] = __builtin_amdgcn_mfma_f32_16x16x32_bf16(
                                          a1[mt][kh], b0[nt][kh], acc[2 + mt][nt], 0, 0, 0);
        __builtin_amdgcn_s_setprio(0);
        PHASE_BAR();

        // ================= phase 3 =================
        bf16x8 b1[4][2];
#pragma unroll
        for (int nt = 0; nt < 4; ++nt)
#pragma unroll
            for (int kh = 0; kh < 2; ++kh)
                b1[nt][kh] = *fragp(Bhb, (4 + nt) * 16 + frow, kh * 64 + fkq * 16);
        if (j + 2 < L)
            stage_half(A + (size_t)m0 * K + ko0 + (j + 2) * 64, K,
                       Als[bf * 2 + 0], wave, lane);
        PHASE_BAR();
        WAIT_LGKM0();
        __builtin_amdgcn_s_setprio(1);
#pragma unroll
        for (int mt = 0; mt < 2; ++mt)
#pragma unroll
            for (int nt = 0; nt < 4; ++nt)
#pragma unroll
                for (int kh = 0; kh < 2; ++kh)
                    acc[2 + mt][4 + nt] = __builtin_amdgcn_mfma_f32_16x16x32_bf16(
                                              a1[mt][kh], b1[nt][kh], acc[2 + mt][4 + nt], 0, 0, 0);
        __builtin_amdgcn_s_setprio(0);
        PHASE_BAR();

        // ================= phase 4 =================
        if (j + 2 < L) {
            stage_half(B + (size_t)n0 * K + ko0 + (j + 2) * 64,         K,
                       Bls[bf * 2 + 0], wave, lane);
            stage_half(B + (size_t)(n0 + 128) * K + ko0 + (j + 2) * 64, K,
                       Bls[bf * 2 + 1], wave, lane);
        }
        PHASE_BAR();
        WAIT_LGKM0();
        __builtin_amdgcn_s_setprio(1);
#pragma unroll
        for (int mt = 0; mt < 2; ++mt)
#pragma unroll
            for (int nt = 0; nt < 4; ++nt)
#pragma unroll
                for (int kh = 0; kh < 2; ++kh)
                    acc[mt][4 + nt] = __builtin_amdgcn_mfma_f32_16x16x32_bf16(
                                          a0[mt][kh], b1[nt][kh], acc[mt][4 + nt], 0, 0, 0);
        __builtin_amdgcn_s_setprio(0);
        if (j < L - 2) asm volatile("s_waitcnt vmcnt(6)" ::: "memory");
        else           asm volatile("s_waitcnt vmcnt(0)" ::: "memory");
        PHASE_BAR();
    }

    // ---- epilogue: atomic f32 accumulate (HW global_atomic_add_f32) ----
#pragma unroll
    for (int mt = 0; mt < 4; ++mt) {
#pragma unroll
        for (int r = 0; r < 4; ++r) {
            const int s = m0 + wm * 64 + mt * 16 + fkq * 4 + r;
            float* crow = C + (size_t)s * DMODEL + n0 + wn * 128 + frow;
#pragma unroll
            for (int u = 0; u < 8; ++u)
                unsafeAtomicAdd(crow + u * 16, acc[mt][u][r]);
        }
    }
}

// ---------------------------------------------------------------------------
// Flash attention (round-4 verified): swapped QK^T + in-register softmax,
// causal pairing + async dbuf staging.
// ---------------------------------------------------------------------------
__device__ __forceinline__ void attn_tile_swapped(
        const bf16x8 aq[4], f32x4 o_acc[8], float& m_i, float& l_i,
        const __bf16* __restrict__ Kl, const __bf16* __restrict__ Vl,
        int lane, int fr, int fq, int qm, int kbase, bool diag) {
    // ---- QK^T, swapped: S^T[k][m] ----
    f32x4 sT[4];
#pragma unroll
    for (int u = 0; u < 4; ++u) sT[u] = (f32x4){0.f, 0.f, 0.f, 0.f};
    __builtin_amdgcn_s_setprio(1);
#pragma unroll
    for (int u = 0; u < 4; ++u)
#pragma unroll
        for (int ks = 0; ks < 4; ++ks)
            sT[u] = __builtin_amdgcn_mfma_f32_16x16x32_bf16(
                        *(const bf16x8*)&Kl[((u * 4 + ks) * 64 + lane) * 8],
                        aq[ks], sT[u], 0, 0, 0);
    __builtin_amdgcn_s_setprio(0);

    if (diag) {
#pragma unroll
        for (int u = 0; u < 4; ++u)
#pragma unroll
            for (int r = 0; r < 4; ++r)
                if (kbase + u * 16 + fq * 4 + r > qm + fr)
                    sT[u][r] = -INFINITY;
    }

    float mx = sT[0][0];
#pragma unroll
    for (int u = 0; u < 4; ++u)
#pragma unroll
        for (int r = 0; r < 4; ++r) mx = fmaxf(mx, sT[u][r]);
    mx = fmaxf(mx, __shfl_xor(mx, 16));
    mx = fmaxf(mx, __shfl_xor(mx, 32));

    if (__any(mx > m_i + 8.0f)) {
        const float m_new = fmaxf(m_i, mx);
        const float alpha = exp2f(m_i - m_new);
        m_i = m_new;
        l_i *= alpha;
#pragma unroll
        for (int r = 0; r < 4; ++r) {
            const float a = __shfl(alpha, fq * 4 + r);
#pragma unroll
            for (int dt = 0; dt < 8; ++dt) o_acc[dt][r] *= a;
        }
    }

    float p[4][4];
    float ps = 0.f;
#pragma unroll
    for (int u = 0; u < 4; ++u)
#pragma unroll
        for (int r = 0; r < 4; ++r) {
            p[u][r] = exp2f(sT[u][r] - m_i);
            ps += p[u][r];
        }
    ps += __shfl_xor(ps, 16);
    ps += __shfl_xor(ps, 32);
    l_i += ps;

    unsigned pk[4][2];
#pragma unroll
    for (int u = 0; u < 4; ++u)
#pragma unroll
        for (int hh = 0; hh < 2; ++hh)
            asm("v_cvt_pk_bf16_f32 %0, %1, %2"
                : "=v"(pk[u][hh]) : "v"(p[u][2 * hh]), "v"(p[u][2 * hh + 1]));

    const int slA = fr + 16 * ((fq & 1) * 2);
    const int slB = slA + 16;
    bf16x8 ap[2];
#pragma unroll
    for (int ks = 0; ks < 2; ++ks) {
        unsigned w[4];
#pragma unroll
        for (int jp = 0; jp < 4; ++jp) {
            const int sl = (jp & 2) ? slB : slA;
            const unsigned v0 = (unsigned)__shfl((int)pk[2 * ks + 0][jp & 1], sl);
            const unsigned v1 = (unsigned)__shfl((int)pk[2 * ks + 1][jp & 1], sl);
            w[jp] = (fq & 2) ? v1 : v0;
        }
        ap[ks] = __builtin_bit_cast(bf16x8, (uint4){w[0], w[1], w[2], w[3]});
    }

    __builtin_amdgcn_s_setprio(1);
#pragma unroll
    for (int dt = 0; dt < 8; ++dt)
#pragma unroll
        for (int ks = 0; ks < 2; ++ks)
            o_acc[dt] = __builtin_amdgcn_mfma_f32_16x16x32_bf16(
                            ap[ks],
                            *(const bf16x8*)&Vl[((dt * 2 + ks) * 64 + lane) * 8],
                            o_acc[dt], 0, 0, 0);
    __builtin_amdgcn_s_setprio(0);
}

__global__ __launch_bounds__(256, 2) void attn_mfma(const __bf16* __restrict__ Qb,
                                                    const __bf16* __restrict__ Kb,
                                                    const __bf16* __restrict__ Vt,
                                                    u16* __restrict__ Ob) {
    __shared__ __align__(16) __bf16 Kls[2][16 * 64 * 8];  // 2 x 16KB
    __shared__ __align__(16) __bf16 Vls[2][16 * 64 * 8];  // 2 x 16KB

    const int h    = blockIdx.x;
    const int g    = h >> 2;
    const int pair = blockIdx.y;                 // 0..15
    const int ytl  = pair;
    const int yth  = (S_LEN / 64 - 1) - pair;
    const int q0l  = ytl * 64;
    const int q0h  = yth * 64;
    const int tid  = threadIdx.x;
    const int lane = tid & 63;
    const int wave = tid >> 6;
    const int fr   = lane & 15;
    const int fq   = lane >> 4;

    {
        const __bf16* Qh = Qb + ((size_t)h * S_LEN + q0h + wave * 16 + fr) * HD;
        const __bf16* Ql = Qb + ((size_t)h * S_LEN + q0l + wave * 16 + fr) * HD;
#pragma unroll
        for (int ks = 0; ks < 4; ++ks) {
            load16_to_lds(Qh + ks * 32 + fq * 8, &Kls[0][(size_t)((wave * 4 + ks) * 64) * 8]);
            load16_to_lds(Ql + ks * 32 + fq * 8, &Kls[1][(size_t)((wave * 4 + ks) * 64) * 8]);
        }
    }
    __syncthreads();
    bf16x8 aqh[4], aql[4];
#pragma unroll
    for (int ks = 0; ks < 4; ++ks) {
        aqh[ks] = *(const bf16x8*)&Kls[0][((wave * 4 + ks) * 64 + lane) * 8];
        aql[ks] = *(const bf16x8*)&Kls[1][((wave * 4 + ks) * 64 + lane) * 8];
    }
    __syncthreads();

    float m_h = -INFINITY, l_h = 0.f, m_l = -INFINITY, l_l = 0.f;
    f32x4 o_h[8], o_l[8];
#pragma unroll
    for (int dt = 0; dt < 8; ++dt) {
        o_h[dt] = (f32x4){0.f, 0.f, 0.f, 0.f};
        o_l[dt] = (f32x4){0.f, 0.f, 0.f, 0.f};
    }

    {
        const __bf16* Kg = Kb + ((size_t)g * S_LEN + wave * 16 + fr) * HD;
#pragma unroll
        for (int ks = 0; ks < 4; ++ks)
            load16_to_lds(Kg + ks * 32 + fq * 8, &Kls[0][(size_t)((wave * 4 + ks) * 64) * 8]);
#pragma unroll
        for (int i = 0; i < 2; ++i) {
            const int dt = wave * 2 + i;
            const __bf16* Vg = Vt + ((size_t)g * HD + dt * 16 + fr) * S_LEN;
#pragma unroll
            for (int ks = 0; ks < 2; ++ks)
                load16_to_lds(Vg + ks * 32 + fq * 8, &Vls[0][(size_t)((dt * 2 + ks) * 64) * 8]);
        }
    }
    __syncthreads();

    for (int kt = 0; kt <= yth; ++kt) {
        const int buf = kt & 1;
        if (kt < yth) {
            const int nb = buf ^ 1;
            const __bf16* Kg = Kb + ((size_t)g * S_LEN + (kt + 1) * 64 + wave * 16 + fr) * HD;
#pragma unroll
            for (int ks = 0; ks < 4; ++ks)
                load16_to_lds(Kg + ks * 32 + fq * 8, &Kls[nb][(size_t)((wave * 4 + ks) * 64) * 8]);
#pragma unroll
            for (int i = 0; i < 2; ++i) {
                const int dt = wave * 2 + i;
                const __bf16* Vg = Vt + ((size_t)g * HD + dt * 16 + fr) * S_LEN + (kt + 1) * 64;
#pragma unroll
                for (int ks = 0; ks < 2; ++ks)
                    load16_to_lds(Vg + ks * 32 + fq * 8, &Vls[nb][(size_t)((dt * 2 + ks) * 64) * 8]);
            }
        }

        attn_tile_swapped(aqh, o_h, m_h, l_h, Kls[buf], Vls[buf],
                          lane, fr, fq, q0h + wave * 16, kt * 64, kt == yth);
        if (kt <= ytl)
            attn_tile_swapped(aql, o_l, m_l, l_l, Kls[buf], Vls[buf],
                              lane, fr, fq, q0l + wave * 16, kt * 64, kt == ytl);

        __syncthreads();
    }

#pragma unroll
    for (int r = 0; r < 4; ++r) {
        const float ih = 1.0f / __shfl(l_h, fq * 4 + r);
        const float il = 1.0f / __shfl(l_l, fq * 4 + r);
        const int sh = q0h + wave * 16 + fq * 4 + r;
        const int sl = q0l + wave * 16 + fq * 4 + r;
#pragma unroll
        for (int dt = 0; dt < 8; ++dt) {
            Ob[(size_t)sh * QKDIM + h * HD + dt * 16 + fr] = f2bf(o_h[dt][r] * ih);
            Ob[(size_t)sl * QKDIM + h * HD + dt * 16 + fr] = f2bf(o_l[dt][r] * il);
        }
    }
}

// ---------------------------------------------------------------------------
extern "C" void kernel_launch(void* const* d_in, const int* in_sizes, int n_in,
                              void* d_out, int out_size, void* d_ws, size_t ws_size,
                              hipStream_t stream) {
    const float* x  = (const float*)d_in[0];
    const float* Wq = (const float*)d_in[1];
    const float* Wk = (const float*)d_in[2];
    const float* Wv = (const float*)d_in[3];
    const float* Wo = (const float*)d_in[4];
    const float* qw = (const float*)d_in[5];
    const float* kw = (const float*)d_in[6];

    float* out     = (float*)d_out;
    float* cache_k = out + (size_t)S_LEN * DMODEL;
    float* cache_v = cache_k + (size_t)NKV * S_LEN * HD;

    // ---- workspace layout (u16 units from base) ----
    u16* wsu = (u16*)d_ws;
    u16* qrb = wsu;
    u16* kcb = qrb + (size_t)NHEADS * S_LEN * HD;
    u16* vtb = kcb + (size_t)NKV * S_LEN * HD;
    u16* Wqb = vtb + (size_t)NKV * S_LEN * HD;
    u16* Wkb = Wqb + (size_t)QKDIM * DMODEL;
    u16* aob = Wqb;                               // overlay (weights dead)
    u16* Wob = aob + (size_t)S_LEN * QKDIM;
    float* ct = (float*)(Wqb + (size_t)S_LEN * QKDIM + (size_t)DMODEL * QKDIM);
    float* st = ct + S_LEN * 64;
    u16* xb  = (u16*)out;                         // x bf16 in out region

    // 1) input converts + rope tables
    convert_inputs<<<4096, 256, 0, stream>>>(x, Wq, Wk, Wv, xb, Wqb);
    rope_table<<<S_LEN, 64, 0, stream>>>(ct, st);

    // 2) 8-phase fused QKV projection + RMSNorm + RoPE + casts + V transpose
    gemm_qkv_8ph<<<dim3((QKDIM + 2 * KVDIM) / 256, S_LEN / 256), 512, 0, stream>>>(
        (const __bf16*)xb, (const __bf16*)Wqb, (const __bf16*)Wkb,
        ct, st, qw, kw, qrb, cache_k, kcb, cache_v, vtb);

    // 3) zero out + Wo convert (xb dead now), then attention
    prep_outproj<<<2048, 256, 0, stream>>>(Wo, Wob, out);
    attn_mfma<<<dim3(NHEADS, S_LEN / 128), 256, 0, stream>>>(
        (const __bf16*)qrb, (const __bf16*)kcb, (const __bf16*)vtb, aob);

    // 4) output projection: 8-phase 256^2, split-K x3, atomic accumulate
    gemm_out_8ph<<<dim3(DMODEL / 256, S_LEN / 256, 3), 512, 0, stream>>>(
        (const __bf16*)aob, (const __bf16*)Wob, out);
}

// Round 6
// 416.136 us; speedup vs baseline: 1.4170x; 1.0158x over previous
//
#include <hip/hip_runtime.h>
#include <hip/hip_bf16.h>
#include <math.h>

#define S_LEN  2048
#define DMODEL 2560
#define NHEADS 32
#define NKV    8
#define HD     128
#define QKDIM  (NHEADS * HD)   // 4096
#define KVDIM  (NKV * HD)      // 1024

typedef __bf16 bf16x8 __attribute__((ext_vector_type(8)));
typedef float  f32x4  __attribute__((ext_vector_type(4)));
typedef unsigned short u16;

#define AS1 __attribute__((address_space(1)))
#define AS3 __attribute__((address_space(3)))

__device__ __forceinline__ void load16_to_lds(const void* g, void* l) {
    __builtin_amdgcn_global_load_lds((const AS1 void*)g, (AS3 void*)l, 16, 0, 0);
}

__device__ __forceinline__ u16 f2bf(float f) {
    unsigned u = __builtin_bit_cast(unsigned, f);
    return (u16)((u + 0x7fff + ((u >> 16) & 1)) >> 16);   // RTNE
}

// phase-boundary helpers (raw s_barrier; sched_barrier pins ds_reads, rule #18)
#define PHASE_BAR() do { __builtin_amdgcn_sched_barrier(0);            \
                         __builtin_amdgcn_s_barrier();                 \
                         __builtin_amdgcn_sched_barrier(0); } while (0)
#define WAIT_LGKM0() do { asm volatile("s_waitcnt lgkmcnt(0)" ::: "memory"); \
                          __builtin_amdgcn_sched_barrier(0); } while (0)

// LDS XOR-swizzle, 3-bit (G4-verified): byte ^= ((row&7)<<4) for a
// [128 rows][64 cols] bf16 half-tile (row pitch 128B).
__device__ __forceinline__ const bf16x8* fragp(const __bf16* hbase, int row, int colb) {
    int b = (row << 7) | colb;
    b ^= ((b >> 7) & 7) << 4;
    return (const bf16x8*)((const char*)hbase + b);
}

// Staging: global_load_lds writes LINEARLY; swizzle applied by pre-swizzling
// the per-lane GLOBAL source address (same involution).
__device__ __forceinline__ void stage_half(const __bf16* __restrict__ g0, int Kp,
                                           __bf16* l0, int wave, int lane) {
#pragma unroll
    for (int j = 0; j < 2; ++j) {
        const int p = ((wave * 2 + j) << 10) | (lane << 4);   // physical byte
        const int b = p ^ (((p >> 7) & 7) << 4);              // logical byte
        load16_to_lds((const char*)g0 + (size_t)(b >> 7) * (Kp * 2) + (b & 127),
                      (char*)l0 + ((wave * 2 + j) << 10));
    }
}

// ---------------------------------------------------------------------------
// Fused input convert: x | Wq | Wk | Wv -> bf16 in one launch.
// ---------------------------------------------------------------------------
#define N4_X   (S_LEN * DMODEL / 4)
#define N4_WQ  (QKDIM * DMODEL / 4)
#define N4_WK  (KVDIM * DMODEL / 4)
#define N4_ALL (N4_X + N4_WQ + 2 * N4_WK)

__global__ __launch_bounds__(256) void convert_inputs(const float* __restrict__ x,
                                                      const float* __restrict__ wq,
                                                      const float* __restrict__ wk,
                                                      const float* __restrict__ wv,
                                                      u16* __restrict__ xb,
                                                      u16* __restrict__ wb) {
    const int stride = gridDim.x * 256;
    for (int i = blockIdx.x * 256 + threadIdx.x; i < N4_ALL; i += stride) {
        const float4* src;
        ushort4* dst;
        if (i < N4_X) {
            src = (const float4*)x + i;
            dst = (ushort4*)xb + i;
        } else {
            const int j = i - N4_X;
            dst = (ushort4*)wb + j;
            if (j < N4_WQ)                  src = (const float4*)wq + j;
            else if (j < N4_WQ + N4_WK)     src = (const float4*)wk + (j - N4_WQ);
            else                            src = (const float4*)wv + (j - N4_WQ - N4_WK);
        }
        float4 v = *src;
        ushort4 r;
        r.x = f2bf(v.x); r.y = f2bf(v.y); r.z = f2bf(v.z); r.w = f2bf(v.w);
        *dst = r;
    }
}

// ---------------------------------------------------------------------------
// Prep for out-projection: zero the out accumulator (atomic split-K target)
// and convert Wo -> bf16. Must run AFTER gemm_qkv (xb overlays out region).
// ---------------------------------------------------------------------------
#define N4_OUT (S_LEN * DMODEL / 4)     // 1310720
#define N4_WO  (DMODEL * QKDIM / 4)     // 2621440

__global__ __launch_bounds__(256) void prep_outproj(const float* __restrict__ wo,
                                                    u16* __restrict__ wob,
                                                    float* __restrict__ outz) {
    const int stride = gridDim.x * 256;
    for (int i = blockIdx.x * 256 + threadIdx.x; i < N4_OUT + N4_WO; i += stride) {
        if (i < N4_OUT) {
            ((float4*)outz)[i] = (float4){0.f, 0.f, 0.f, 0.f};
        } else {
            const int j = i - N4_OUT;
            float4 v = ((const float4*)wo)[j];
            ushort4 r;
            r.x = f2bf(v.x); r.y = f2bf(v.y); r.z = f2bf(v.z); r.w = f2bf(v.w);
            ((ushort4*)wob)[j] = r;
        }
    }
}

__global__ __launch_bounds__(64) void rope_table(float* __restrict__ ct,
                                                 float* __restrict__ st) {
    const int s = blockIdx.x;
    const int i = threadIdx.x;
    const double invf = pow(5.0e6, -(double)i / 64.0);
    const double ang  = (double)s * invf;
    ct[s * 64 + i] = (float)cos(ang);
    st[s * 64 + i] = (float)sin(ang);
}

// ---------------------------------------------------------------------------
// 256x256 8-phase QKV GEMM with fused RMSNorm/RoPE/cast/V-transpose epilogue.
// (verified rounds 2-5; 3-bit swizzle, counted vmcnt, setprio)
// ---------------------------------------------------------------------------
__global__ __launch_bounds__(512, 2) void gemm_qkv_8ph(const __bf16* __restrict__ A,
                                                       const __bf16* __restrict__ Bq,
                                                       const __bf16* __restrict__ Bkv,
                                                       const float* __restrict__ ct,
                                                       const float* __restrict__ st,
                                                       const float* __restrict__ qw,
                                                       const float* __restrict__ kw,
                                                       u16*   __restrict__ qrb,
                                                       float* __restrict__ kc,
                                                       u16*   __restrict__ kcb,
                                                       float* __restrict__ vc,
                                                       u16*   __restrict__ vtb) {
    __shared__ __align__(16) __bf16 Als[4][128 * 64];   // [buf*2+half] 64KB
    __shared__ __align__(16) __bf16 Bls[4][128 * 64];   // 64KB

    const int K   = DMODEL;
    const int nkt = K / 64;                  // 40
    const int n0g = blockIdx.x * 256;
    const __bf16* B;
    int n0;
    if (n0g < QKDIM) { B = Bq;  n0 = n0g; }
    else             { B = Bkv; n0 = n0g - QKDIM; }
    const int m0 = blockIdx.y * 256;

    const int tid  = threadIdx.x;
    const int lane = tid & 63;
    const int wave = tid >> 6;
    const int wm   = wave >> 1;              // 0..3: 64-row band
    const int wn   = wave & 1;               // 0..1: 128-col half (one head)
    const int frow = lane & 15;
    const int fkq  = lane >> 4;
    const int ha   = wm >> 1;                // A half this wave reads
    const int ar0  = (wm & 1) * 64 + frow;   // base row within A half

    f32x4 acc[4][8];
#pragma unroll
    for (int t = 0; t < 4; ++t)
#pragma unroll
        for (int u = 0; u < 8; ++u)
            acc[t][u] = (f32x4){0.f, 0.f, 0.f, 0.f};

    // -------- prologue: kt0 (4 halves) + kt1 {A0,B0,B1}; vmcnt(6) => kt0 in
    stage_half(A + (size_t)m0 * K,               K, Als[0], wave, lane);
    stage_half(A + (size_t)(m0 + 128) * K,       K, Als[1], wave, lane);
    stage_half(B + (size_t)n0 * K,               K, Bls[0], wave, lane);
    stage_half(B + (size_t)(n0 + 128) * K,       K, Bls[1], wave, lane);
    stage_half(A + (size_t)m0 * K + 64,          K, Als[2], wave, lane);
    stage_half(B + (size_t)n0 * K + 64,          K, Bls[2], wave, lane);
    stage_half(B + (size_t)(n0 + 128) * K + 64,  K, Bls[3], wave, lane);
    asm volatile("s_waitcnt vmcnt(6)" ::: "memory");
    PHASE_BAR();

    for (int kt = 0; kt < nkt; ++kt) {
        const int bf = kt & 1;
        const __bf16* Ahb = Als[bf * 2 + ha];
        const __bf16* Bhb = Bls[bf * 2 + wn];

        // ================= phase 1: Q(m01, n0-3) =================
        bf16x8 a0[2][2], b0[4][2];
#pragma unroll
        for (int mt = 0; mt < 2; ++mt)
#pragma unroll
            for (int kh = 0; kh < 2; ++kh)
                a0[mt][kh] = *fragp(Ahb, ar0 + mt * 16, kh * 64 + fkq * 16);
#pragma unroll
        for (int nt = 0; nt < 4; ++nt)
#pragma unroll
            for (int kh = 0; kh < 2; ++kh)
                b0[nt][kh] = *fragp(Bhb, nt * 16 + frow, kh * 64 + fkq * 16);
        if (kt + 1 < nkt)
            stage_half(A + (size_t)(m0 + 128) * K + (kt + 1) * 64, K,
                       Als[(bf ^ 1) * 2 + 1], wave, lane);
        asm volatile("s_waitcnt lgkmcnt(8)" ::: "memory");
        PHASE_BAR();
        WAIT_LGKM0();
        __builtin_amdgcn_s_setprio(1);
#pragma unroll
        for (int mt = 0; mt < 2; ++mt)
#pragma unroll
            for (int nt = 0; nt < 4; ++nt)
#pragma unroll
                for (int kh = 0; kh < 2; ++kh)
                    acc[mt][nt] = __builtin_amdgcn_mfma_f32_16x16x32_bf16(
                                      a0[mt][kh], b0[nt][kh], acc[mt][nt], 0, 0, 0);
        __builtin_amdgcn_s_setprio(0);
        PHASE_BAR();

        // ================= phase 2: Q(m23, n0-3) =================
        bf16x8 a1[2][2];
#pragma unroll
        for (int mt = 0; mt < 2; ++mt)
#pragma unroll
            for (int kh = 0; kh < 2; ++kh)
                a1[mt][kh] = *fragp(Ahb, ar0 + 32 + mt * 16, kh * 64 + fkq * 16);
        PHASE_BAR();
        WAIT_LGKM0();
        __builtin_amdgcn_s_setprio(1);
#pragma unroll
        for (int mt = 0; mt < 2; ++mt)
#pragma unroll
            for (int nt = 0; nt < 4; ++nt)
#pragma unroll
                for (int kh = 0; kh < 2; ++kh)
                    acc[2 + mt][nt] = __builtin_amdgcn_mfma_f32_16x16x32_bf16(
                                          a1[mt][kh], b0[nt][kh], acc[2 + mt][nt], 0, 0, 0);
        __builtin_amdgcn_s_setprio(0);
        PHASE_BAR();

        // ================= phase 3: Q(m23, n4-7) =================
        bf16x8 b1[4][2];
#pragma unroll
        for (int nt = 0; nt < 4; ++nt)
#pragma unroll
            for (int kh = 0; kh < 2; ++kh)
                b1[nt][kh] = *fragp(Bhb, (4 + nt) * 16 + frow, kh * 64 + fkq * 16);
        if (kt + 2 < nkt)
            stage_half(A + (size_t)m0 * K + (kt + 2) * 64, K,
                       Als[bf * 2 + 0], wave, lane);
        PHASE_BAR();
        WAIT_LGKM0();
        __builtin_amdgcn_s_setprio(1);
#pragma unroll
        for (int mt = 0; mt < 2; ++mt)
#pragma unroll
            for (int nt = 0; nt < 4; ++nt)
#pragma unroll
                for (int kh = 0; kh < 2; ++kh)
                    acc[2 + mt][4 + nt] = __builtin_amdgcn_mfma_f32_16x16x32_bf16(
                                              a1[mt][kh], b1[nt][kh], acc[2 + mt][4 + nt], 0, 0, 0);
        __builtin_amdgcn_s_setprio(0);
        PHASE_BAR();

        // ================= phase 4: Q(m01, n4-7) =================
        if (kt + 2 < nkt) {
            stage_half(B + (size_t)n0 * K + (kt + 2) * 64,         K,
                       Bls[bf * 2 + 0], wave, lane);
            stage_half(B + (size_t)(n0 + 128) * K + (kt + 2) * 64, K,
                       Bls[bf * 2 + 1], wave, lane);
        }
        PHASE_BAR();
        WAIT_LGKM0();
        __builtin_amdgcn_s_setprio(1);
#pragma unroll
        for (int mt = 0; mt < 2; ++mt)
#pragma unroll
            for (int nt = 0; nt < 4; ++nt)
#pragma unroll
                for (int kh = 0; kh < 2; ++kh)
                    acc[mt][4 + nt] = __builtin_amdgcn_mfma_f32_16x16x32_bf16(
                                          a0[mt][kh], b1[nt][kh], acc[mt][4 + nt], 0, 0, 0);
        __builtin_amdgcn_s_setprio(0);
        if (kt < nkt - 2) asm volatile("s_waitcnt vmcnt(6)" ::: "memory");
        else              asm volatile("s_waitcnt vmcnt(0)" ::: "memory");
        PHASE_BAR();
    }

    // ------------------ fused epilogue (within-wave) ------------------
    const int fr = frow;
    const int fq = fkq;
    const int nw = n0g + wn * 128;
    if (n0g < QKDIM + KVDIM) {
        const int isQ = (n0g < QKDIM) ? 1 : 0;
        const float* w = isQ ? qw : kw;
        float wv[8];
#pragma unroll
        for (int u = 0; u < 8; ++u) wv[u] = w[u * 16 + fr];

#pragma unroll
        for (int mt = 0; mt < 4; ++mt) {
#pragma unroll
            for (int r = 0; r < 4; ++r) {
                float ss = 0.f;
#pragma unroll
                for (int u = 0; u < 8; ++u) ss += acc[mt][u][r] * acc[mt][u][r];
                ss += __shfl_xor(ss, 1);
                ss += __shfl_xor(ss, 2);
                ss += __shfl_xor(ss, 4);
                ss += __shfl_xor(ss, 8);
                const float rstd = rsqrtf(ss * (1.0f / 128.0f) + 1e-6f);
                const int s = m0 + wm * 64 + mt * 16 + fq * 4 + r;
#pragma unroll
                for (int u = 0; u < 4; ++u) {
                    const float cs  = ct[s * 64 + u * 16 + fr];
                    const float sn  = st[s * 64 + u * 16 + fr];
                    const float ylo = acc[mt][u][r]     * rstd * wv[u];
                    const float yhi = acc[mt][u + 4][r] * rstd * wv[u + 4];
                    const float olo = ylo * cs - yhi * sn;
                    const float ohi = yhi * cs + ylo * sn;
                    if (isQ) {
                        const int h = nw >> 7;
                        const size_t base = ((size_t)h * S_LEN + s) * HD;
                        qrb[base + u * 16 + fr]       = f2bf(olo * 0.12751743f);
                        qrb[base + (u + 4) * 16 + fr] = f2bf(ohi * 0.12751743f);
                    } else {
                        const int g = (nw - QKDIM) >> 7;
                        const size_t base = ((size_t)g * S_LEN + s) * HD;
                        kc [base + u * 16 + fr]       = olo;
                        kc [base + (u + 4) * 16 + fr] = ohi;
                        kcb[base + u * 16 + fr]       = f2bf(olo);
                        kcb[base + (u + 4) * 16 + fr] = f2bf(ohi);
                    }
                }
            }
        }
    } else {
        const int g = (nw - QKDIM - KVDIM) >> 7;
#pragma unroll
        for (int mt = 0; mt < 4; ++mt) {
            const int sb = m0 + wm * 64 + mt * 16 + fq * 4;   // 4 consecutive s
#pragma unroll
            for (int u = 0; u < 8; ++u) {
                const int d = u * 16 + fr;
                ushort4 o;
                o.x = f2bf(acc[mt][u][0]); o.y = f2bf(acc[mt][u][1]);
                o.z = f2bf(acc[mt][u][2]); o.w = f2bf(acc[mt][u][3]);
                *(ushort4*)&vtb[((size_t)g * HD + d) * S_LEN + sb] = o;
#pragma unroll
                for (int r = 0; r < 4; ++r)
                    vc[((size_t)g * S_LEN + sb + r) * HD + d] = acc[mt][u][r];
            }
        }
    }
}

// ---------------------------------------------------------------------------
// Output projection (verified round 5): 256x256 8-phase + split-K x3,
// atomic f32 accumulation into the pre-zeroed out buffer.
// ---------------------------------------------------------------------------
__global__ __launch_bounds__(512, 2) void gemm_out_8ph(const __bf16* __restrict__ A,
                                                       const __bf16* __restrict__ B,
                                                       float* __restrict__ C) {
    __shared__ __align__(16) __bf16 Als[4][128 * 64];   // 64KB
    __shared__ __align__(16) __bf16 Bls[4][128 * 64];   // 64KB

    const int K   = QKDIM;                   // 4096
    const int z   = blockIdx.z;
    const int ks0 = (z == 0) ? 0 : 22 + (z - 1) * 21;
    const int L   = (z == 0) ? 22 : 21;      // local K-tile count
    const int ko0 = ks0 * 64;
    const int n0  = blockIdx.x * 256;
    const int m0  = blockIdx.y * 256;

    const int tid  = threadIdx.x;
    const int lane = tid & 63;
    const int wave = tid >> 6;
    const int wm   = wave >> 1;
    const int wn   = wave & 1;
    const int frow = lane & 15;
    const int fkq  = lane >> 4;
    const int ha   = wm >> 1;
    const int ar0  = (wm & 1) * 64 + frow;

    f32x4 acc[4][8];
#pragma unroll
    for (int t = 0; t < 4; ++t)
#pragma unroll
        for (int u = 0; u < 8; ++u)
            acc[t][u] = (f32x4){0.f, 0.f, 0.f, 0.f};

    // prologue: tile ks0 (4 halves) + ks0+1 {A0,B0,B1}; vmcnt(6) => ks0 in
    stage_half(A + (size_t)m0 * K + ko0,              K, Als[0], wave, lane);
    stage_half(A + (size_t)(m0 + 128) * K + ko0,      K, Als[1], wave, lane);
    stage_half(B + (size_t)n0 * K + ko0,              K, Bls[0], wave, lane);
    stage_half(B + (size_t)(n0 + 128) * K + ko0,      K, Bls[1], wave, lane);
    stage_half(A + (size_t)m0 * K + ko0 + 64,         K, Als[2], wave, lane);
    stage_half(B + (size_t)n0 * K + ko0 + 64,         K, Bls[2], wave, lane);
    stage_half(B + (size_t)(n0 + 128) * K + ko0 + 64, K, Bls[3], wave, lane);
    asm volatile("s_waitcnt vmcnt(6)" ::: "memory");
    PHASE_BAR();

    for (int j = 0; j < L; ++j) {
        const int bf = j & 1;
        const __bf16* Ahb = Als[bf * 2 + ha];
        const __bf16* Bhb = Bls[bf * 2 + wn];

        // ================= phase 1 =================
        bf16x8 a0[2][2], b0[4][2];
#pragma unroll
        for (int mt = 0; mt < 2; ++mt)
#pragma unroll
            for (int kh = 0; kh < 2; ++kh)
                a0[mt][kh] = *fragp(Ahb, ar0 + mt * 16, kh * 64 + fkq * 16);
#pragma unroll
        for (int nt = 0; nt < 4; ++nt)
#pragma unroll
            for (int kh = 0; kh < 2; ++kh)
                b0[nt][kh] = *fragp(Bhb, nt * 16 + frow, kh * 64 + fkq * 16);
        if (j + 1 < L)
            stage_half(A + (size_t)(m0 + 128) * K + ko0 + (j + 1) * 64, K,
                       Als[(bf ^ 1) * 2 + 1], wave, lane);
        asm volatile("s_waitcnt lgkmcnt(8)" ::: "memory");
        PHASE_BAR();
        WAIT_LGKM0();
        __builtin_amdgcn_s_setprio(1);
#pragma unroll
        for (int mt = 0; mt < 2; ++mt)
#pragma unroll
            for (int nt = 0; nt < 4; ++nt)
#pragma unroll
                for (int kh = 0; kh < 2; ++kh)
                    acc[mt][nt] = __builtin_amdgcn_mfma_f32_16x16x32_bf16(
                                      a0[mt][kh], b0[nt][kh], acc[mt][nt], 0, 0, 0);
        __builtin_amdgcn_s_setprio(0);
        PHASE_BAR();

        // ================= phase 2 =================
        bf16x8 a1[2][2];
#pragma unroll
        for (int mt = 0; mt < 2; ++mt)
#pragma unroll
            for (int kh = 0; kh < 2; ++kh)
                a1[mt][kh] = *fragp(Ahb, ar0 + 32 + mt * 16, kh * 64 + fkq * 16);
        PHASE_BAR();
        WAIT_LGKM0();
        __builtin_amdgcn_s_setprio(1);
#pragma unroll
        for (int mt = 0; mt < 2; ++mt)
#pragma unroll
            for (int nt = 0; nt < 4; ++nt)
#pragma unroll
                for (int kh = 0; kh < 2; ++kh)
                    acc[2 + mt][nt] = __builtin_amdgcn_mfma_f32_16x16x32_bf16(
                                          a1[mt][kh], b0[nt][kh], acc[2 + mt][nt], 0, 0, 0);
        __builtin_amdgcn_s_setprio(0);
        PHASE_BAR();

        // ================= phase 3 =================
        bf16x8 b1[4][2];
#pragma unroll
        for (int nt = 0; nt < 4; ++nt)
#pragma unroll
            for (int kh = 0; kh < 2; ++kh)
                b1[nt][kh] = *fragp(Bhb, (4 + nt) * 16 + frow, kh * 64 + fkq * 16);
        if (j + 2 < L)
            stage_half(A + (size_t)m0 * K + ko0 + (j + 2) * 64, K,
                       Als[bf * 2 + 0], wave, lane);
        PHASE_BAR();
        WAIT_LGKM0();
        __builtin_amdgcn_s_setprio(1);
#pragma unroll
        for (int mt = 0; mt < 2; ++mt)
#pragma unroll
            for (int nt = 0; nt < 4; ++nt)
#pragma unroll
                for (int kh = 0; kh < 2; ++kh)
                    acc[2 + mt][4 + nt] = __builtin_amdgcn_mfma_f32_16x16x32_bf16(
                                              a1[mt][kh], b1[nt][kh], acc[2 + mt][4 + nt], 0, 0, 0);
        __builtin_amdgcn_s_setprio(0);
        PHASE_BAR();

        // ================= phase 4 =================
        if (j + 2 < L) {
            stage_half(B + (size_t)n0 * K + ko0 + (j + 2) * 64,         K,
                       Bls[bf * 2 + 0], wave, lane);
            stage_half(B + (size_t)(n0 + 128) * K + ko0 + (j + 2) * 64, K,
                       Bls[bf * 2 + 1], wave, lane);
        }
        PHASE_BAR();
        WAIT_LGKM0();
        __builtin_amdgcn_s_setprio(1);
#pragma unroll
        for (int mt = 0; mt < 2; ++mt)
#pragma unroll
            for (int nt = 0; nt < 4; ++nt)
#pragma unroll
                for (int kh = 0; kh < 2; ++kh)
                    acc[mt][4 + nt] = __builtin_amdgcn_mfma_f32_16x16x32_bf16(
                                          a0[mt][kh], b1[nt][kh], acc[mt][4 + nt], 0, 0, 0);
        __builtin_amdgcn_s_setprio(0);
        if (j < L - 2) asm volatile("s_waitcnt vmcnt(6)" ::: "memory");
        else           asm volatile("s_waitcnt vmcnt(0)" ::: "memory");
        PHASE_BAR();
    }

    // ---- epilogue: atomic f32 accumulate (HW global_atomic_add_f32) ----
#pragma unroll
    for (int mt = 0; mt < 4; ++mt) {
#pragma unroll
        for (int r = 0; r < 4; ++r) {
            const int s = m0 + wm * 64 + mt * 16 + fkq * 4 + r;
            float* crow = C + (size_t)s * DMODEL + n0 + wn * 128 + frow;
#pragma unroll
            for (int u = 0; u < 8; ++u)
                unsafeAtomicAdd(crow + u * 16, acc[mt][u][r]);
        }
    }
}

// ---------------------------------------------------------------------------
// Flash attention, round 6: single q-tile per block (1024 blocks, tail-first)
// + 48KB LDS (K single-buffer, V double-buffer) -> 3 blocks/CU = 12 waves/CU
// (was 512 uniform paired blocks pinned at 2 blocks/CU = 8 waves/CU).
// Schedule per k-tile: stage V(kt+1) early (dbuf); QK^T consumes K; raw
// barrier releases Kls; restage K(kt+1) in-place hidden under softmax+PV;
// end __syncthreads drains vmcnt. Swapped-QK^T in-register softmax
// (round-4 verified algebra, unchanged).
// ---------------------------------------------------------------------------
__global__ __launch_bounds__(256, 3) void attn_mfma(const __bf16* __restrict__ Qb,
                                                    const __bf16* __restrict__ Kb,
                                                    const __bf16* __restrict__ Vt,
                                                    u16* __restrict__ Ob) {
    __shared__ __align__(16) __bf16 Kls[16 * 64 * 8];     // 16KB (single)
    __shared__ __align__(16) __bf16 Vls[2][16 * 64 * 8];  // 2 x 16KB

    const int h    = blockIdx.x;
    const int g    = h >> 2;
    const int yt   = (S_LEN / 64 - 1) - blockIdx.y;   // tail-first: 31..0
    const int q0   = yt * 64;
    const int tid  = threadIdx.x;
    const int lane = tid & 63;
    const int wave = tid >> 6;
    const int fr   = lane & 15;
    const int fq   = lane >> 4;
    const int qm   = q0 + wave * 16;

    // stage Q tile into Vls[0] scratch, hoist to regs
    {
        const __bf16* Qg = Qb + ((size_t)h * S_LEN + q0 + wave * 16 + fr) * HD;
#pragma unroll
        for (int ks = 0; ks < 4; ++ks)
            load16_to_lds(Qg + ks * 32 + fq * 8, &Vls[0][(size_t)((wave * 4 + ks) * 64) * 8]);
    }
    __syncthreads();
    bf16x8 aq[4];
#pragma unroll
    for (int ks = 0; ks < 4; ++ks)
        aq[ks] = *(const bf16x8*)&Vls[0][((wave * 4 + ks) * 64 + lane) * 8];
    __syncthreads();   // hoist done before Vls[0] reused

    float m_i = -INFINITY, l_i = 0.f;
    f32x4 o_acc[8];
#pragma unroll
    for (int dt = 0; dt < 8; ++dt) o_acc[dt] = (f32x4){0.f, 0.f, 0.f, 0.f};

    // stage kt=0: K -> Kls, V -> Vls[0]
    {
        const __bf16* Kg = Kb + ((size_t)g * S_LEN + wave * 16 + fr) * HD;
#pragma unroll
        for (int ks = 0; ks < 4; ++ks)
            load16_to_lds(Kg + ks * 32 + fq * 8, &Kls[(size_t)((wave * 4 + ks) * 64) * 8]);
#pragma unroll
        for (int i = 0; i < 2; ++i) {
            const int dt = wave * 2 + i;
            const __bf16* Vg = Vt + ((size_t)g * HD + dt * 16 + fr) * S_LEN;
#pragma unroll
            for (int ks = 0; ks < 2; ++ks)
                load16_to_lds(Vg + ks * 32 + fq * 8, &Vls[0][(size_t)((dt * 2 + ks) * 64) * 8]);
        }
    }
    __syncthreads();   // kt=0 staged

    for (int kt = 0; kt <= yt; ++kt) {
        const int vb = kt & 1;

        // ---- stage V(kt+1) early into the other V buffer ----
        if (kt < yt) {
#pragma unroll
            for (int i = 0; i < 2; ++i) {
                const int dt = wave * 2 + i;
                const __bf16* Vg = Vt + ((size_t)g * HD + dt * 16 + fr) * S_LEN + (kt + 1) * 64;
#pragma unroll
                for (int ks = 0; ks < 2; ++ks)
                    load16_to_lds(Vg + ks * 32 + fq * 8,
                                  &Vls[vb ^ 1][(size_t)((dt * 2 + ks) * 64) * 8]);
            }
        }

        // ---- QK^T, swapped: S^T[k][m] ----
        f32x4 sT[4];
#pragma unroll
        for (int u = 0; u < 4; ++u) sT[u] = (f32x4){0.f, 0.f, 0.f, 0.f};
        __builtin_amdgcn_s_setprio(1);
#pragma unroll
        for (int u = 0; u < 4; ++u)
#pragma unroll
            for (int ks = 0; ks < 4; ++ks)
                sT[u] = __builtin_amdgcn_mfma_f32_16x16x32_bf16(
                            *(const bf16x8*)&Kls[((u * 4 + ks) * 64 + lane) * 8],
                            aq[ks], sT[u], 0, 0, 0);
        __builtin_amdgcn_s_setprio(0);

        // ---- Kls consumed by all waves; restage K(kt+1) in place ----
        PHASE_BAR();
        if (kt < yt) {
            const __bf16* Kg = Kb + ((size_t)g * S_LEN + (kt + 1) * 64 + wave * 16 + fr) * HD;
#pragma unroll
            for (int ks = 0; ks < 4; ++ks)
                load16_to_lds(Kg + ks * 32 + fq * 8, &Kls[(size_t)((wave * 4 + ks) * 64) * 8]);
        }

        // ---- causal mask (diag tile): k > q ----
        if (kt == yt) {
#pragma unroll
            for (int u = 0; u < 4; ++u)
#pragma unroll
                for (int r = 0; r < 4; ++r)
                    if (kt * 64 + u * 16 + fq * 4 + r > qm + fr)
                        sT[u][r] = -INFINITY;
        }

        // ---- row max: 15 reg-max + 2 shfl ----
        float mx = sT[0][0];
#pragma unroll
        for (int u = 0; u < 4; ++u)
#pragma unroll
            for (int r = 0; r < 4; ++r) mx = fmaxf(mx, sT[u][r]);
        mx = fmaxf(mx, __shfl_xor(mx, 16));
        mx = fmaxf(mx, __shfl_xor(mx, 32));

        // ---- defer-max (T13, THR=8) ----
        if (__any(mx > m_i + 8.0f)) {
            const float m_new = fmaxf(m_i, mx);
            const float alpha = exp2f(m_i - m_new);
            m_i = m_new;
            l_i *= alpha;
#pragma unroll
            for (int r = 0; r < 4; ++r) {
                const float a = __shfl(alpha, fq * 4 + r);
#pragma unroll
                for (int dt = 0; dt < 8; ++dt) o_acc[dt][r] *= a;
            }
        }

        // ---- P = 2^(s - m), row-sum ----
        float p[4][4];
        float ps = 0.f;
#pragma unroll
        for (int u = 0; u < 4; ++u)
#pragma unroll
            for (int r = 0; r < 4; ++r) {
                p[u][r] = exp2f(sT[u][r] - m_i);
                ps += p[u][r];
            }
        ps += __shfl_xor(ps, 16);
        ps += __shfl_xor(ps, 32);
        l_i += ps;

        // ---- pack + in-register transpose to PV A-fragments ----
        unsigned pk[4][2];
#pragma unroll
        for (int u = 0; u < 4; ++u)
#pragma unroll
            for (int hh = 0; hh < 2; ++hh)
                asm("v_cvt_pk_bf16_f32 %0, %1, %2"
                    : "=v"(pk[u][hh]) : "v"(p[u][2 * hh]), "v"(p[u][2 * hh + 1]));

        const int slA = fr + 16 * ((fq & 1) * 2);
        const int slB = slA + 16;
        bf16x8 ap[2];
#pragma unroll
        for (int ks = 0; ks < 2; ++ks) {
            unsigned w[4];
#pragma unroll
            for (int jp = 0; jp < 4; ++jp) {
                const int sl = (jp & 2) ? slB : slA;
                const unsigned v0 = (unsigned)__shfl((int)pk[2 * ks + 0][jp & 1], sl);
                const unsigned v1 = (unsigned)__shfl((int)pk[2 * ks + 1][jp & 1], sl);
                w[jp] = (fq & 2) ? v1 : v0;
            }
            ap[ks] = __builtin_bit_cast(bf16x8, (uint4){w[0], w[1], w[2], w[3]});
        }

        // ---- PV (reads Vls[vb]) ----
        __builtin_amdgcn_s_setprio(1);
#pragma unroll
        for (int dt = 0; dt < 8; ++dt)
#pragma unroll
            for (int ks = 0; ks < 2; ++ks)
                o_acc[dt] = __builtin_amdgcn_mfma_f32_16x16x32_bf16(
                                ap[ks],
                                *(const bf16x8*)&Vls[vb][((dt * 2 + ks) * 64 + lane) * 8],
                                o_acc[dt], 0, 0, 0);
        __builtin_amdgcn_s_setprio(0);

        __syncthreads();   // drains vmcnt: K(kt+1), V(kt+1) staged
    }

    // ---- epilogue (l per column m=fr -> shfl to o-row m) ----
#pragma unroll
    for (int r = 0; r < 4; ++r) {
        const float inv_l = 1.0f / __shfl(l_i, fq * 4 + r);
        const int s = q0 + wave * 16 + fq * 4 + r;
#pragma unroll
        for (int dt = 0; dt < 8; ++dt)
            Ob[(size_t)s * QKDIM + h * HD + dt * 16 + fr] = f2bf(o_acc[dt][r] * inv_l);
    }
}

// ---------------------------------------------------------------------------
extern "C" void kernel_launch(void* const* d_in, const int* in_sizes, int n_in,
                              void* d_out, int out_size, void* d_ws, size_t ws_size,
                              hipStream_t stream) {
    const float* x  = (const float*)d_in[0];
    const float* Wq = (const float*)d_in[1];
    const float* Wk = (const float*)d_in[2];
    const float* Wv = (const float*)d_in[3];
    const float* Wo = (const float*)d_in[4];
    const float* qw = (const float*)d_in[5];
    const float* kw = (const float*)d_in[6];

    float* out     = (float*)d_out;
    float* cache_k = out + (size_t)S_LEN * DMODEL;
    float* cache_v = cache_k + (size_t)NKV * S_LEN * HD;

    // ---- workspace layout (u16 units from base) ----
    u16* wsu = (u16*)d_ws;
    u16* qrb = wsu;
    u16* kcb = qrb + (size_t)NHEADS * S_LEN * HD;
    u16* vtb = kcb + (size_t)NKV * S_LEN * HD;
    u16* Wqb = vtb + (size_t)NKV * S_LEN * HD;
    u16* Wkb = Wqb + (size_t)QKDIM * DMODEL;
    u16* aob = Wqb;                               // overlay (weights dead)
    u16* Wob = aob + (size_t)S_LEN * QKDIM;
    float* ct = (float*)(Wqb + (size_t)S_LEN * QKDIM + (size_t)DMODEL * QKDIM);
    float* st = ct + S_LEN * 64;
    u16* xb  = (u16*)out;                         // x bf16 in out region

    // 1) input converts + rope tables
    convert_inputs<<<4096, 256, 0, stream>>>(x, Wq, Wk, Wv, xb, Wqb);
    rope_table<<<S_LEN, 64, 0, stream>>>(ct, st);

    // 2) 8-phase fused QKV projection + RMSNorm + RoPE + casts + V transpose
    gemm_qkv_8ph<<<dim3((QKDIM + 2 * KVDIM) / 256, S_LEN / 256), 512, 0, stream>>>(
        (const __bf16*)xb, (const __bf16*)Wqb, (const __bf16*)Wkb,
        ct, st, qw, kw, qrb, cache_k, kcb, cache_v, vtb);

    // 3) zero out + Wo convert (xb dead now), then attention
    prep_outproj<<<2048, 256, 0, stream>>>(Wo, Wob, out);
    attn_mfma<<<dim3(NHEADS, S_LEN / 64), 256, 0, stream>>>(
        (const __bf16*)qrb, (const __bf16*)kcb, (const __bf16*)vtb, aob);

    // 4) output projection: 8-phase 256^2, split-K x3, atomic accumulate
    gemm_out_8ph<<<dim3(DMODEL / 256, S_LEN / 256, 3), 512, 0, stream>>>(
        (const __bf16*)aob, (const __bf16*)Wob, out);
}